// Round 5
// baseline (504.887 us; speedup 1.0000x reference)
//
#include <hip/hip_runtime.h>

// Problem constants
#define N_NODES 4096
#define C_IN    256
#define HID     256
#define BATCH   8
#define R_TOT   32768   // BATCH * N_NODES

typedef unsigned short u16;
typedef short s8v  __attribute__((ext_vector_type(8)));   // 8 bf16 (bit pattern in shorts)
typedef float f4v  __attribute__((ext_vector_type(4)));
typedef float f16v __attribute__((ext_vector_type(16)));
typedef u16   u16x4 __attribute__((ext_vector_type(4)));

#define MFMA(a,b,c)   __builtin_amdgcn_mfma_f32_16x16x32_bf16((a),(b),(c),0,0,0)
#define MFMA32(a,b,c) __builtin_amdgcn_mfma_f32_32x32x16_bf16((a),(b),(c),0,0,0)

__device__ __forceinline__ u16 bf_rne(float x) {
    unsigned u = __float_as_uint(x);
    u += 0x7fffu + ((u >> 16) & 1u);
    return (u16)(u >> 16);
}
__device__ __forceinline__ float bf_f(u16 h) {
    return __uint_as_float(((unsigned)h) << 16);
}
// fp32 -> bf16 hi/lo split: x ~= hi + lo, |err| <= 2^-18 |x|
__device__ __forceinline__ void split2f(float x, u16& h, u16& l) {
    h = bf_rne(x);
    l = bf_rne(x - bf_f(h));
}

// async global->LDS, 16B per lane. lds ptr must be wave-uniform (dest = base + lane*16)
__device__ __forceinline__ void glds16(const void* g, void* l) {
    __builtin_amdgcn_global_load_lds(
        (const __attribute__((address_space(1))) void*)g,
        (__attribute__((address_space(3))) void*)l, 16, 0, 0);
}

// ---------------- split kernels ----------------

__global__ void splitK_k(const float* __restrict__ in, u16* __restrict__ oh,
                         u16* __restrict__ ol, int n4) {
    int i = blockIdx.x * blockDim.x + threadIdx.x;
    int stride = gridDim.x * blockDim.x;
    for (; i < n4; i += stride) {
        float4 x = ((const float4*)in)[i];
        u16x4 hh, ll; u16 a, b;
        split2f(x.x, a, b); hh[0] = a; ll[0] = b;
        split2f(x.y, a, b); hh[1] = a; ll[1] = b;
        split2f(x.z, a, b); hh[2] = a; ll[2] = b;
        split2f(x.w, a, b); hh[3] = a; ll[3] = b;
        ((u16x4*)oh)[i] = hh; ((u16x4*)ol)[i] = ll;
    }
}

// transpose + split for the 256x256 weight matrices: out[h][c] = in[c][h]
__global__ void splitT_k(const float* __restrict__ in, u16* __restrict__ oh,
                         u16* __restrict__ ol) {
    int c = blockIdx.x;      // row of in
    int h = threadIdx.x;     // col of in
    float v = in[c * 256 + h];
    u16 hi, lo; split2f(v, hi, lo);
    oh[h * 256 + c] = hi;
    ol[h * 256 + c] = lo;
}

// ---------------- small GEMM (unchanged, proven): T[i=hid'][j=r] ----------------
__global__ __launch_bounds__(256, 2) void gemm_small_k(
    const u16* __restrict__ Ah, const u16* __restrict__ Al,
    const float* __restrict__ Bf, const float* __restrict__ bias,
    u16* __restrict__ Oh, u16* __restrict__ Ol)
{
    __shared__ u16 sAh[4096], sAl[4096], sBh[4096], sBl[4096];  // 128x32 each
    const int tid = threadIdx.x;
    const int w = tid >> 6, lane = tid & 63;
    const int i0 = blockIdx.x * 128;   // output row tile (hid')
    const int r0 = blockIdx.y * 128;   // output col tile (r)
    const int lr = lane & 15, lk = lane >> 4;
    const int wr = (w >> 1) * 64, wc = (w & 1) * 64;
    const int kslot = (lk ^ ((lr >> 1) & 3)) * 8;   // swizzled read slot (u16 units)

    const u16 *pAh[2], *pAl[2];
    const int cb = ((lane & 3) ^ ((lane >> 3) & 3)) * 8;  // pre-swizzled source slot
#pragma unroll
    for (int j = 0; j < 2; ++j) {
        const int ra = i0 + (w * 2 + j) * 16 + (lane >> 2);
        pAh[j] = Ah + (size_t)ra * 256 + cb;
        pAl[j] = Al + (size_t)ra * 256 + cb;
    }

    f4v acc[4][4] = {};

    for (int kt = 0; kt < 8; ++kt) {
#pragma unroll
        for (int j = 0; j < 2; ++j) {
            glds16(pAh[j] + kt * 32, sAh + (w * 2 + j) * 512);
            glds16(pAl[j] + kt * 32, sAl + (w * 2 + j) * 512);
        }
#pragma unroll
        for (int i = 0; i < 4; ++i) {
            const int cc  = tid + i * 256;
            const int row = cc >> 3;
            const int col = (((((cc & 7) >> 1) ^ ((cc >> 4) & 3)) << 3)) | ((cc & 1) * 4);
            const float* src = Bf + (size_t)(r0 + row) * 256 + kt * 32 + (cc & 7) * 4;
            float4 x = *(const float4*)src;
            u16x4 hh, ll; u16 a, b;
            split2f(x.x, a, b); hh[0] = a; ll[0] = b;
            split2f(x.y, a, b); hh[1] = a; ll[1] = b;
            split2f(x.z, a, b); hh[2] = a; ll[2] = b;
            split2f(x.w, a, b); hh[3] = a; ll[3] = b;
            *(u16x4*)(sBh + row * 32 + col) = hh;
            *(u16x4*)(sBl + row * 32 + col) = ll;
        }
        __syncthreads();

        s8v fah[4], fal[4], fbh[4], fbl[4];
#pragma unroll
        for (int m = 0; m < 4; ++m) {
            fah[m] = *(const s8v*)(sAh + (wr + m * 16 + lr) * 32 + kslot);
            fal[m] = *(const s8v*)(sAl + (wr + m * 16 + lr) * 32 + kslot);
            fbh[m] = *(const s8v*)(sBh + (wc + m * 16 + lr) * 32 + kslot);
            fbl[m] = *(const s8v*)(sBl + (wc + m * 16 + lr) * 32 + kslot);
        }
#pragma unroll
        for (int m = 0; m < 4; ++m)
#pragma unroll
            for (int n = 0; n < 4; ++n)
                acc[m][n] = MFMA(fah[m], fbh[n], acc[m][n]);
#pragma unroll
        for (int m = 0; m < 4; ++m)
#pragma unroll
            for (int n = 0; n < 4; ++n)
                acc[m][n] = MFMA(fah[m], fbl[n], acc[m][n]);
#pragma unroll
        for (int m = 0; m < 4; ++m)
#pragma unroll
            for (int n = 0; n < 4; ++n)
                acc[m][n] = MFMA(fal[m], fbh[n], acc[m][n]);
        __syncthreads();
    }

#pragma unroll
    for (int m = 0; m < 4; ++m) {
#pragma unroll
        for (int q = 0; q < 4; ++q) {
            const int rowg = i0 + wr + m * 16 + lk * 4 + q;
            const float bv = bias[rowg];
#pragma unroll
            for (int n = 0; n < 4; ++n) {
                const int colg = r0 + wc + n * 16 + lr;
                float v = acc[m][n][q] + bv;
                u16 hi, lo; split2f(v, hi, lo);
                const size_t off = (size_t)rowg * R_TOT + colg;
                Oh[off] = hi; Ol[off] = lo;
            }
        }
    }
}

// ---------------- big GEMM: H[b][i=n][j=h] = relu( sum_m G[i][m] * Tt[j][b*4096+m] ) ----------------
// BM=256 BN=128 BK=32, 8 waves (4Mx2N, per-wave 64x64 = 2x2 of 32x32 MFMA),
// triple-buffered LDS (3 x 48KB), 4 phases/K-tile, counted vmcnt(6) once per tile,
// setprio around MFMA clusters. Same LDS tile format + staging swizzle as before;
// 32x32 fragment reads use slot = (ks*2 + (l>>5)) ^ ((l>>1)&3).
// Buffer layout (u16): [A-hi 256x32 | A-lo 256x32 | B-hi 128x32 | B-lo 128x32] = 24576 u16.
__global__ __launch_bounds__(512, 2) void gemm_big_k(
    const u16* __restrict__ Gh, const u16* __restrict__ Gl,
    const u16* __restrict__ Th, const u16* __restrict__ Tl,
    float* __restrict__ Hout)
{
    extern __shared__ u16 lds[];   // 3 * 24576 u16 = 147456 B
    const int tid = threadIdx.x;
    const int w = tid >> 6, l = tid & 63;
    const int n0 = blockIdx.x * 256;
    const int h0 = blockIdx.y * 128;
    const int b  = blockIdx.z;
    const int l31 = l & 31;
    const int xl  = (l >> 1) & 3;
    const int hw  = l >> 5;
    const int slotk0 = ((0 + hw) ^ xl) * 8;   // k-step 0 read slot (u16 units)
    const int slotk1 = ((2 + hw) ^ xl) * 8;   // k-step 1 read slot
    const int wm = w >> 1, wn = w & 1;

    const int cb = ((l & 3) ^ ((l >> 3) & 3)) * 8;  // pre-swizzled source slot
    const u16* pAh0 = Gh + (size_t)(n0 + 16 * w + (l >> 2)) * 4096 + cb;
    const u16* pAh1 = pAh0 + 128 * 4096;
    const u16* pAl0 = Gl + (size_t)(n0 + 16 * w + (l >> 2)) * 4096 + cb;
    const u16* pAl1 = pAl0 + 128 * 4096;
    const u16* pBh  = Th + (size_t)(h0 + (tid >> 2)) * R_TOT + (size_t)b * 4096 + cb;
    const u16* pBl  = Tl + (size_t)(h0 + (tid >> 2)) * R_TOT + (size_t)b * 4096 + cb;

    // wave-uniform LDS stage bases (u16 units)
    const int aw0 = (16 * w) * 32;           // A j=0; j=1 adds 4096
    const int bw  = 16384 + (16 * w) * 32;   // B-hi; B-lo adds 4096

    f16v acc[2][2] = {};

#define STAGE6(STG) do {                                                       \
    u16* Ls = lds + (STG) * 24576;                                             \
    glds16(pAh0, Ls + aw0);                                                    \
    glds16(pAh1, Ls + aw0 + 4096);                                             \
    glds16(pAl0, Ls + 8192 + aw0);                                             \
    glds16(pAl1, Ls + 8192 + aw0 + 4096);                                      \
    glds16(pBh,  Ls + bw);                                                     \
    glds16(pBl,  Ls + bw + 4096);                                              \
    pAh0 += 32; pAh1 += 32; pAl0 += 32; pAl1 += 32; pBh += 32; pBl += 32;      \
} while (0)

// One K-tile: 4 phases. VMODE: 0 = vmcnt(6) (steady), 1 = vmcnt(0) (drain), 2 = skip.
#define KTILE(CUR, STG, DO_STAGE, VMODE) do {                                  \
    const u16* Lc = lds + (CUR) * 24576;                                       \
    u16* Ls = lds + (STG) * 24576;                                             \
    s8v fah[2][2], fal[2][2], fbh[2][2], fbl[2][2];                            \
    /* P0: read A-hi + B-hi (all ks), stage A-hi pair */                       \
    _Pragma("unroll") for (int m = 0; m < 2; ++m) {                            \
        fah[m][0] = *(const s8v*)(Lc + (wm * 64 + m * 32 + l31) * 32 + slotk0);\
        fah[m][1] = *(const s8v*)(Lc + (wm * 64 + m * 32 + l31) * 32 + slotk1);\
    }                                                                          \
    _Pragma("unroll") for (int n = 0; n < 2; ++n) {                            \
        fbh[n][0] = *(const s8v*)(Lc + 16384 + (wn * 64 + n * 32 + l31) * 32 + slotk0); \
        fbh[n][1] = *(const s8v*)(Lc + 16384 + (wn * 64 + n * 32 + l31) * 32 + slotk1); \
    }                                                                          \
    if (DO_STAGE) { glds16(pAh0, Ls + aw0); glds16(pAh1, Ls + aw0 + 4096); }   \
    __builtin_amdgcn_s_barrier();                                              \
    __builtin_amdgcn_s_setprio(1);                                             \
    _Pragma("unroll") for (int m = 0; m < 2; ++m)                              \
        _Pragma("unroll") for (int n = 0; n < 2; ++n)                          \
            acc[m][n] = MFMA32(fah[m][0], fbh[n][0], acc[m][n]);               \
    __builtin_amdgcn_s_setprio(0);                                             \
    __builtin_amdgcn_s_barrier();                                              \
    /* P1: read B-lo, stage A-lo pair */                                       \
    _Pragma("unroll") for (int n = 0; n < 2; ++n) {                            \
        fbl[n][0] = *(const s8v*)(Lc + 20480 + (wn * 64 + n * 32 + l31) * 32 + slotk0); \
        fbl[n][1] = *(const s8v*)(Lc + 20480 + (wn * 64 + n * 32 + l31) * 32 + slotk1); \
    }                                                                          \
    if (DO_STAGE) { glds16(pAl0, Ls + 8192 + aw0); glds16(pAl1, Ls + 8192 + aw0 + 4096); } \
    __builtin_amdgcn_s_barrier();                                              \
    __builtin_amdgcn_s_setprio(1);                                             \
    _Pragma("unroll") for (int m = 0; m < 2; ++m)                              \
        _Pragma("unroll") for (int n = 0; n < 2; ++n)                          \
            acc[m][n] = MFMA32(fah[m][1], fbh[n][1], acc[m][n]);               \
    __builtin_amdgcn_s_setprio(0);                                             \
    __builtin_amdgcn_s_barrier();                                              \
    /* P2: read A-lo, stage B pair, advance ptrs */                            \
    _Pragma("unroll") for (int m = 0; m < 2; ++m) {                            \
        fal[m][0] = *(const s8v*)(Lc + 8192 + (wm * 64 + m * 32 + l31) * 32 + slotk0); \
        fal[m][1] = *(const s8v*)(Lc + 8192 + (wm * 64 + m * 32 + l31) * 32 + slotk1); \
    }                                                                          \
    if (DO_STAGE) { glds16(pBh, Ls + bw); glds16(pBl, Ls + bw + 4096);         \
        pAh0 += 32; pAh1 += 32; pAl0 += 32; pAl1 += 32; pBh += 32; pBl += 32; } \
    __builtin_amdgcn_s_barrier();                                              \
    __builtin_amdgcn_s_setprio(1);                                             \
    _Pragma("unroll") for (int ks = 0; ks < 2; ++ks)                           \
        _Pragma("unroll") for (int m = 0; m < 2; ++m)                          \
            _Pragma("unroll") for (int n = 0; n < 2; ++n)                      \
                acc[m][n] = MFMA32(fah[m][ks], fbl[n][ks], acc[m][n]);         \
    __builtin_amdgcn_s_setprio(0);                                             \
    __builtin_amdgcn_s_barrier();                                              \
    /* P3: Al*Bh, tile-end wait */                                             \
    __builtin_amdgcn_s_setprio(1);                                             \
    _Pragma("unroll") for (int ks = 0; ks < 2; ++ks)                           \
        _Pragma("unroll") for (int m = 0; m < 2; ++m)                          \
            _Pragma("unroll") for (int n = 0; n < 2; ++n)                      \
                acc[m][n] = MFMA32(fal[m][ks], fbh[n][ks], acc[m][n]);         \
    __builtin_amdgcn_s_setprio(0);                                             \
    if (VMODE == 0)      asm volatile("s_waitcnt vmcnt(6)" ::: "memory");      \
    else if (VMODE == 1) asm volatile("s_waitcnt vmcnt(0)" ::: "memory");      \
    if (VMODE != 2) __builtin_amdgcn_s_barrier();                              \
    __builtin_amdgcn_sched_barrier(0);                                         \
} while (0)

    // prologue: stage tiles 0 (buf0) and 1 (buf1)
    STAGE6(0);
    STAGE6(1);
    asm volatile("s_waitcnt vmcnt(6)" ::: "memory");   // tile-0 loads landed
    __builtin_amdgcn_s_barrier();
    __builtin_amdgcn_sched_barrier(0);

    // main loop: tiles 0..125 (42 x 3), tile t in buf t%3, staging t+2 into (t+2)%3
    for (int it = 0; it < 42; ++it) {
        KTILE(0, 2, 1, 0);
        KTILE(1, 0, 1, 0);
        KTILE(2, 1, 1, 0);
    }
    KTILE(0, 2, 0, 1);   // tile 126: drain tile-127 loads
    KTILE(1, 0, 0, 2);   // tile 127: nothing outstanding

#undef STAGE6
#undef KTILE

    // epilogue: relu, store fp32 H[b*4096+row][col]
    // C/D 32x32 layout: col = l&31, row = (q&3) + 8*(q>>2) + 4*(l>>5)
    float* outp = Hout + ((size_t)b * 4096 + n0 + wm * 64) * 256 + h0 + wn * 64 + l31;
    const int r4 = hw * 4;
#pragma unroll
    for (int m = 0; m < 2; ++m)
#pragma unroll
        for (int n = 0; n < 2; ++n)
#pragma unroll
            for (int q = 0; q < 16; ++q) {
                const int row = m * 32 + (q & 3) + 8 * (q >> 2) + r4;
                float v = acc[m][n][q];
                v = v > 0.f ? v : 0.f;
                outp[(size_t)row * 256 + n * 32] = v;
            }
}

// ---------------- final MLP: out[r] = relu(H[r,:] @ Wm1 + bm1) @ Wm2 + bm2 ----------------
__global__ __launch_bounds__(256) void mlp_k(
    const float* __restrict__ H, const float* __restrict__ Wm1,
    const float* __restrict__ bm1, const float* __restrict__ Wm2,
    const float* __restrict__ bm2, float* __restrict__ out)
{
    __shared__ float rb[4][256];
    const int w = threadIdx.x >> 6, lane = threadIdx.x & 63;
    const int gw0 = blockIdx.x * 4 + w;
    const int stride = gridDim.x * 4;
    for (int r = gw0; r < R_TOT; r += stride) {
        float4 v = *(const float4*)(H + (size_t)r * 256 + lane * 4);
        *(float4*)&rb[w][lane * 4] = v;
        __syncthreads();
        float acc = 0.f;
#pragma unroll 8
        for (int k = 0; k < 256; ++k)
            acc = fmaf(rb[w][k], Wm1[k * 64 + lane], acc);
        float m = acc + bm1[lane];
        m = m > 0.f ? m : 0.f;
        float s = m * Wm2[lane];
#pragma unroll
        for (int off = 32; off; off >>= 1) s += __shfl_down(s, off);
        if (lane == 0) out[r] = s + bm2[0];
        __syncthreads();
    }
}

// ---------------- launch ----------------
extern "C" void kernel_launch(void* const* d_in, const int* in_sizes, int n_in,
                              void* d_out, int out_size, void* d_ws, size_t ws_size,
                              hipStream_t stream) {
    (void)in_sizes; (void)n_in; (void)out_size; (void)ws_size;
    const float* X   = (const float*)d_in[0];
    const float* G   = (const float*)d_in[1];
    const float* W1  = (const float*)d_in[2];
    const float* b1  = (const float*)d_in[3];
    const float* W2  = (const float*)d_in[4];
    const float* b2  = (const float*)d_in[5];
    const float* Wm1 = (const float*)d_in[6];
    const float* bm1 = (const float*)d_in[7];
    const float* Wm2 = (const float*)d_in[8];
    const float* bm2 = (const float*)d_in[9];
    float* out = (float*)d_out;

    char* ws = (char*)d_ws;
    u16* Gh   = (u16*)(ws);                     // 33554432 B
    u16* Gl   = (u16*)(ws + 33554432u);         // 33554432 B
    u16* W1th = (u16*)(ws + 67108864u);         // 131072 B
    u16* W1tl = (u16*)(ws + 67239936u);
    u16* W2th = (u16*)(ws + 67371008u);
    u16* W2tl = (u16*)(ws + 67502080u);
    u16* Tth  = (u16*)(ws + 67633152u);         // 16777216 B
    u16* Ttl  = (u16*)(ws + 84410368u);         // 16777216 B
    float* Hb = (float*)(ws + 101187584u);      // 33554432 B  (total 134742016 B)

    splitK_k<<<2048, 256, 0, stream>>>(G, Gh, Gl, 16777216 / 4);
    splitT_k<<<256, 256, 0, stream>>>(W1, W1th, W1tl);
    splitT_k<<<256, 256, 0, stream>>>(W2, W2th, W2tl);

    // conv1 pre-prop: T1t = (X @ W1 + b1)^T, split
    gemm_small_k<<<dim3(2, 256), 256, 0, stream>>>(W1th, W1tl, X, b1, Tth, Ttl);
    // conv1 prop: H1 = relu(G @ T1)
    gemm_big_k<<<dim3(16, 2, 8), 512, 147456, stream>>>(Gh, Gl, Tth, Ttl, Hb);
    // conv2 pre-prop: T2t = (H1 @ W2 + b2)^T, split
    gemm_small_k<<<dim3(2, 256), 256, 0, stream>>>(W2th, W2tl, Hb, b2, Tth, Ttl);
    // conv2 prop: H2 = relu(G @ T2)
    gemm_big_k<<<dim3(16, 2, 8), 512, 147456, stream>>>(Gh, Gl, Tth, Ttl, Hb);
    // final MLP
    mlp_k<<<2048, 256, 0, stream>>>(Hb, Wm1, bm1, Wm2, bm2, out);
}

// Round 6
// 460.903 us; speedup vs baseline: 1.0954x; 1.0954x over previous
//
#include <hip/hip_runtime.h>

// Problem constants
#define N_NODES 4096
#define C_IN    256
#define HID     256
#define BATCH   8
#define R_TOT   32768   // BATCH * N_NODES

typedef unsigned short u16;
typedef short s8v  __attribute__((ext_vector_type(8)));   // 8 bf16 (bit pattern in shorts)
typedef float f4v  __attribute__((ext_vector_type(4)));
typedef u16   u16x4 __attribute__((ext_vector_type(4)));

#define MFMA(a,b,c) __builtin_amdgcn_mfma_f32_16x16x32_bf16((a),(b),(c),0,0,0)

__device__ __forceinline__ u16 bf_rne(float x) {
    unsigned u = __float_as_uint(x);
    u += 0x7fffu + ((u >> 16) & 1u);
    return (u16)(u >> 16);
}
__device__ __forceinline__ float bf_f(u16 h) {
    return __uint_as_float(((unsigned)h) << 16);
}
// fp32 -> bf16 hi/lo split: x ~= hi + lo, |err| <= 2^-18 |x|
__device__ __forceinline__ void split2f(float x, u16& h, u16& l) {
    h = bf_rne(x);
    l = bf_rne(x - bf_f(h));
}

// async global->LDS, 16B per lane. lds ptr must be wave-uniform (dest = base + lane*16)
__device__ __forceinline__ void glds16(const void* g, void* l) {
    __builtin_amdgcn_global_load_lds(
        (const __attribute__((address_space(1))) void*)g,
        (__attribute__((address_space(3))) void*)l, 16, 0, 0);
}

// ---------------- split kernels ----------------

// fused elementwise split of G (4096x4096) and X (32768x256), float4-vectorized
__global__ void splitGX_k(const float* __restrict__ G, u16* __restrict__ Gh,
                          u16* __restrict__ Gl, const float* __restrict__ X,
                          u16* __restrict__ Xh, u16* __restrict__ Xl) {
    const int nG = 4194304;              // 16M floats / 4
    const int nTot = nG + 2097152;       // + 8M floats / 4
    int i = blockIdx.x * blockDim.x + threadIdx.x;
    const int stride = gridDim.x * blockDim.x;
    for (; i < nTot; i += stride) {
        const float4* src; u16x4* dh; u16x4* dl; int j;
        if (i < nG) { src = (const float4*)G; dh = (u16x4*)Gh; dl = (u16x4*)Gl; j = i; }
        else        { src = (const float4*)X; dh = (u16x4*)Xh; dl = (u16x4*)Xl; j = i - nG; }
        float4 x = src[j];
        u16x4 hh, ll; u16 a, b;
        split2f(x.x, a, b); hh[0] = a; ll[0] = b;
        split2f(x.y, a, b); hh[1] = a; ll[1] = b;
        split2f(x.z, a, b); hh[2] = a; ll[2] = b;
        split2f(x.w, a, b); hh[3] = a; ll[3] = b;
        dh[j] = hh; dl[j] = ll;
    }
}

// transpose + split for both 256x256 weight matrices: out[h][c] = in[c][h]
__global__ void splitT2_k(const float* __restrict__ W1, u16* __restrict__ W1th,
                          u16* __restrict__ W1tl, const float* __restrict__ W2,
                          u16* __restrict__ W2th, u16* __restrict__ W2tl) {
    const float* in = blockIdx.y ? W2 : W1;
    u16* oh = blockIdx.y ? W2th : W1th;
    u16* ol = blockIdx.y ? W2tl : W1tl;
    const int c = blockIdx.x;      // row of in
    const int h = threadIdx.x;     // col of in
    float v = in[c * 256 + h];
    u16 hi, lo; split2f(v, hi, lo);
    oh[h * 256 + c] = hi;
    ol[h * 256 + c] = lo;
}

// ---------------- small GEMM: T[i=hid'][j=r] = sum_k Wt[i][k] * B[j][k] + bias[i] ----------------
// A (Wt) and B both pre-split bf16, all four tiles staged via glds16 (pre-swizzled source).
// Output written split hi/lo, transposed layout [256][32768]. No relu.
__global__ __launch_bounds__(256, 2) void gemm_small_k(
    const u16* __restrict__ Ah, const u16* __restrict__ Al,
    const u16* __restrict__ Bh, const u16* __restrict__ Bl,
    const float* __restrict__ bias,
    u16* __restrict__ Oh, u16* __restrict__ Ol)
{
    __shared__ u16 sAh[4096], sAl[4096], sBh[4096], sBl[4096];  // 128x32 each
    const int tid = threadIdx.x;
    const int w = tid >> 6, lane = tid & 63;
    const int i0 = blockIdx.x * 128;   // output row tile (hid')
    const int r0 = blockIdx.y * 128;   // output col tile (r)
    const int lr = lane & 15, lk = lane >> 4;
    const int wr = (w >> 1) * 64, wc = (w & 1) * 64;
    const int kslot = (lk ^ ((lr >> 1) & 3)) * 8;   // swizzled read slot (u16 units)
    const int cb = ((lane & 3) ^ ((lane >> 3) & 3)) * 8;  // pre-swizzled source slot

    const u16 *pAh[2], *pAl[2], *pBh[2], *pBl[2];
#pragma unroll
    for (int j = 0; j < 2; ++j) {
        const int ra = i0 + (w * 2 + j) * 16 + (lane >> 2);
        pAh[j] = Ah + (size_t)ra * 256 + cb;
        pAl[j] = Al + (size_t)ra * 256 + cb;
        const int rb = r0 + (w * 2 + j) * 16 + (lane >> 2);
        pBh[j] = Bh + (size_t)rb * 256 + cb;
        pBl[j] = Bl + (size_t)rb * 256 + cb;
    }

    f4v acc[4][4] = {};

    for (int kt = 0; kt < 8; ++kt) {
#pragma unroll
        for (int j = 0; j < 2; ++j) {
            glds16(pAh[j] + kt * 32, sAh + (w * 2 + j) * 512);
            glds16(pAl[j] + kt * 32, sAl + (w * 2 + j) * 512);
            glds16(pBh[j] + kt * 32, sBh + (w * 2 + j) * 512);
            glds16(pBl[j] + kt * 32, sBl + (w * 2 + j) * 512);
        }
        __syncthreads();

        s8v fah[4], fal[4], fbh[4], fbl[4];
#pragma unroll
        for (int m = 0; m < 4; ++m) {
            fah[m] = *(const s8v*)(sAh + (wr + m * 16 + lr) * 32 + kslot);
            fal[m] = *(const s8v*)(sAl + (wr + m * 16 + lr) * 32 + kslot);
            fbh[m] = *(const s8v*)(sBh + (wc + m * 16 + lr) * 32 + kslot);
            fbl[m] = *(const s8v*)(sBl + (wc + m * 16 + lr) * 32 + kslot);
        }
#pragma unroll
        for (int m = 0; m < 4; ++m)
#pragma unroll
            for (int n = 0; n < 4; ++n)
                acc[m][n] = MFMA(fah[m], fbh[n], acc[m][n]);
#pragma unroll
        for (int m = 0; m < 4; ++m)
#pragma unroll
            for (int n = 0; n < 4; ++n)
                acc[m][n] = MFMA(fah[m], fbl[n], acc[m][n]);
#pragma unroll
        for (int m = 0; m < 4; ++m)
#pragma unroll
            for (int n = 0; n < 4; ++n)
                acc[m][n] = MFMA(fal[m], fbh[n], acc[m][n]);
        __syncthreads();
    }

    // epilogue: +bias, split, store transposed output [hid'][32768]
#pragma unroll
    for (int m = 0; m < 4; ++m) {
#pragma unroll
        for (int q = 0; q < 4; ++q) {
            const int rowg = i0 + wr + m * 16 + lk * 4 + q;
            const float bv = bias[rowg];
#pragma unroll
            for (int n = 0; n < 4; ++n) {
                const int colg = r0 + wc + n * 16 + lr;
                float v = acc[m][n][q] + bv;
                u16 hi, lo; split2f(v, hi, lo);
                const size_t off = (size_t)rowg * R_TOT + colg;
                Oh[off] = hi; Ol[off] = lo;
            }
        }
    }
}

// ---------------- big GEMM: H[b][i=n][j=h] = relu( sum_m G[i][m] * Tt[j][b*4096+m] ) ----------------
// Round-3 proven structure: BM=256 BN=128 BK=32, 8 waves (4Mx2N, per-wave 64x64),
// triple-buffered LDS (3 x 48KB), 4 phases/K-tile, counted vmcnt(6) once per tile,
// setprio around MFMA clusters, 16x16x32 MFMA. Output now written SPLIT hi/lo bf16.
// Buffer layout (u16): [A-hi 256x32 | A-lo 256x32 | B-hi 128x32 | B-lo 128x32] = 24576 u16.
__global__ __launch_bounds__(512, 2) void gemm_big_k(
    const u16* __restrict__ Gh, const u16* __restrict__ Gl,
    const u16* __restrict__ Th, const u16* __restrict__ Tl,
    u16* __restrict__ Hh, u16* __restrict__ Hl)
{
    extern __shared__ u16 lds[];   // 3 * 24576 u16 = 147456 B
    const int tid = threadIdx.x;
    const int w = tid >> 6, l = tid & 63;
    const int n0 = blockIdx.x * 256;
    const int h0 = blockIdx.y * 128;
    const int b  = blockIdx.z;
    const int lr = l & 15, lk = l >> 4;
    const int kslot8 = (lk ^ ((lr >> 1) & 3)) * 8;  // swizzled read slot (u16)
    const int wm = w >> 1, wn = w & 1;

    const int cb = ((l & 3) ^ ((l >> 3) & 3)) * 8;  // pre-swizzled source slot
    const u16* pAh0 = Gh + (size_t)(n0 + 16 * w + (l >> 2)) * 4096 + cb;
    const u16* pAh1 = pAh0 + 128 * 4096;
    const u16* pAl0 = Gl + (size_t)(n0 + 16 * w + (l >> 2)) * 4096 + cb;
    const u16* pAl1 = pAl0 + 128 * 4096;
    const u16* pBh  = Th + (size_t)(h0 + (tid >> 2)) * R_TOT + (size_t)b * 4096 + cb;
    const u16* pBl  = Tl + (size_t)(h0 + (tid >> 2)) * R_TOT + (size_t)b * 4096 + cb;

    // wave-uniform LDS stage bases (u16 units)
    const int aw0 = (16 * w) * 32;           // A j=0; j=1 adds 4096
    const int bw  = 16384 + (16 * w) * 32;   // B-hi; B-lo adds 4096

    f4v acc[4][4] = {};

#define STAGE6(STG) do {                                                       \
    u16* Ls = lds + (STG) * 24576;                                             \
    glds16(pAh0, Ls + aw0);                                                    \
    glds16(pAh1, Ls + aw0 + 4096);                                             \
    glds16(pAl0, Ls + 8192 + aw0);                                             \
    glds16(pAl1, Ls + 8192 + aw0 + 4096);                                      \
    glds16(pBh,  Ls + bw);                                                     \
    glds16(pBl,  Ls + bw + 4096);                                              \
    pAh0 += 32; pAh1 += 32; pAl0 += 32; pAl1 += 32; pBh += 32; pBl += 32;      \
} while (0)

// One K-tile: 4 phases. VMODE: 0 = vmcnt(6) (steady), 1 = vmcnt(0) (drain), 2 = skip.
#define KTILE(CUR, STG, DO_STAGE, VMODE) do {                                  \
    const u16* Lc = lds + (CUR) * 24576;                                       \
    u16* Ls = lds + (STG) * 24576;                                             \
    s8v fah[4], fal[4], fbh[4], fbl[4];                                        \
    /* P0: read A-hi + B-hi, stage A-hi pair */                                \
    _Pragma("unroll") for (int m = 0; m < 4; ++m)                              \
        fah[m] = *(const s8v*)(Lc + (wm * 64 + m * 16 + lr) * 32 + kslot8);    \
    _Pragma("unroll") for (int n = 0; n < 4; ++n)                              \
        fbh[n] = *(const s8v*)(Lc + 16384 + (wn * 64 + n * 16 + lr) * 32 + kslot8); \
    if (DO_STAGE) { glds16(pAh0, Ls + aw0); glds16(pAh1, Ls + aw0 + 4096); }   \
    __builtin_amdgcn_s_barrier();                                              \
    __builtin_amdgcn_s_setprio(1);                                             \
    _Pragma("unroll") for (int m = 0; m < 2; ++m)                              \
        _Pragma("unroll") for (int n = 0; n < 4; ++n)                          \
            acc[m][n] = MFMA(fah[m], fbh[n], acc[m][n]);                       \
    __builtin_amdgcn_s_setprio(0);                                             \
    __builtin_amdgcn_s_barrier();                                              \
    /* P1: read B-lo, stage A-lo pair */                                       \
    _Pragma("unroll") for (int n = 0; n < 4; ++n)                              \
        fbl[n] = *(const s8v*)(Lc + 20480 + (wn * 64 + n * 16 + lr) * 32 + kslot8); \
    if (DO_STAGE) { glds16(pAl0, Ls + 8192 + aw0); glds16(pAl1, Ls + 8192 + aw0 + 4096); } \
    __builtin_amdgcn_s_barrier();                                              \
    __builtin_amdgcn_s_setprio(1);                                             \
    _Pragma("unroll") for (int m = 2; m < 4; ++m)                              \
        _Pragma("unroll") for (int n = 0; n < 4; ++n)                          \
            acc[m][n] = MFMA(fah[m], fbh[n], acc[m][n]);                       \
    __builtin_amdgcn_s_setprio(0);                                             \
    __builtin_amdgcn_s_barrier();                                              \
    /* P2: read A-lo, stage B pair, advance ptrs */                            \
    _Pragma("unroll") for (int m = 0; m < 4; ++m)                              \
        fal[m] = *(const s8v*)(Lc + 8192 + (wm * 64 + m * 16 + lr) * 32 + kslot8); \
    if (DO_STAGE) { glds16(pBh, Ls + bw); glds16(pBl, Ls + bw + 4096);         \
        pAh0 += 32; pAh1 += 32; pAl0 += 32; pAl1 += 32; pBh += 32; pBl += 32; } \
    __builtin_amdgcn_s_barrier();                                              \
    __builtin_amdgcn_s_setprio(1);                                             \
    _Pragma("unroll") for (int m = 0; m < 4; ++m)                              \
        _Pragma("unroll") for (int n = 0; n < 4; ++n)                          \
            acc[m][n] = MFMA(fah[m], fbl[n], acc[m][n]);                       \
    __builtin_amdgcn_s_setprio(0);                                             \
    __builtin_amdgcn_s_barrier();                                              \
    /* P3: Al*Bh, tile-end wait */                                             \
    __builtin_amdgcn_s_setprio(1);                                             \
    _Pragma("unroll") for (int m = 0; m < 4; ++m)                              \
        _Pragma("unroll") for (int n = 0; n < 4; ++n)                          \
            acc[m][n] = MFMA(fal[m], fbh[n], acc[m][n]);                       \
    __builtin_amdgcn_s_setprio(0);                                             \
    if (VMODE == 0)      asm volatile("s_waitcnt vmcnt(6)" ::: "memory");      \
    else if (VMODE == 1) asm volatile("s_waitcnt vmcnt(0)" ::: "memory");      \
    if (VMODE != 2) __builtin_amdgcn_s_barrier();                              \
    __builtin_amdgcn_sched_barrier(0);                                         \
} while (0)

    // prologue: stage tiles 0 (buf0) and 1 (buf1)
    STAGE6(0);
    STAGE6(1);
    asm volatile("s_waitcnt vmcnt(6)" ::: "memory");   // tile-0 loads landed
    __builtin_amdgcn_s_barrier();
    __builtin_amdgcn_sched_barrier(0);

    // main loop: tiles 0..125 (42 x 3), tile t in buf t%3, staging t+2 into (t+2)%3
    for (int it = 0; it < 42; ++it) {
        KTILE(0, 2, 1, 0);
        KTILE(1, 0, 1, 0);
        KTILE(2, 1, 1, 0);
    }
    KTILE(0, 2, 0, 1);   // tile 126: drain tile-127 loads
    KTILE(1, 0, 0, 2);   // tile 127: nothing outstanding

#undef STAGE6
#undef KTILE

    // epilogue: relu, split, store H as hi/lo bf16 [b*4096+row][col]
    const size_t obase = ((size_t)b * 4096 + n0 + wm * 64 + lk * 4) * 256
                       + h0 + wn * 64 + lr;
#pragma unroll
    for (int m = 0; m < 4; ++m)
#pragma unroll
        for (int n = 0; n < 4; ++n)
#pragma unroll
            for (int q = 0; q < 4; ++q) {
                float v = acc[m][n][q];
                v = v > 0.f ? v : 0.f;
                u16 hi, lo; split2f(v, hi, lo);
                const size_t off = obase + (size_t)(m * 16 + q) * 256 + n * 16;
                Hh[off] = hi; Hl[off] = lo;
            }
}

// ---------------- final MLP: out[r] = relu(H[r,:] @ Wm1 + bm1) @ Wm2 + bm2 ----------------
__global__ __launch_bounds__(256) void mlp_k(
    const u16* __restrict__ Hh, const u16* __restrict__ Hl,
    const float* __restrict__ Wm1, const float* __restrict__ bm1,
    const float* __restrict__ Wm2, const float* __restrict__ bm2,
    float* __restrict__ out)
{
    __shared__ float rb[4][256];
    const int w = threadIdx.x >> 6, lane = threadIdx.x & 63;
    const int gw0 = blockIdx.x * 4 + w;
    const int stride = gridDim.x * 4;
    for (int r = gw0; r < R_TOT; r += stride) {
        u16x4 hh = *(const u16x4*)(Hh + (size_t)r * 256 + lane * 4);
        u16x4 ll = *(const u16x4*)(Hl + (size_t)r * 256 + lane * 4);
#pragma unroll
        for (int j = 0; j < 4; ++j)
            rb[w][lane * 4 + j] = bf_f(hh[j]) + bf_f(ll[j]);
        __syncthreads();
        float acc = 0.f;
#pragma unroll 8
        for (int k = 0; k < 256; ++k)
            acc = fmaf(rb[w][k], Wm1[k * 64 + lane], acc);
        float m = acc + bm1[lane];
        m = m > 0.f ? m : 0.f;
        float s = m * Wm2[lane];
#pragma unroll
        for (int off = 32; off; off >>= 1) s += __shfl_down(s, off);
        if (lane == 0) out[r] = s + bm2[0];
        __syncthreads();
    }
}

// ---------------- launch ----------------
extern "C" void kernel_launch(void* const* d_in, const int* in_sizes, int n_in,
                              void* d_out, int out_size, void* d_ws, size_t ws_size,
                              hipStream_t stream) {
    (void)in_sizes; (void)n_in; (void)out_size; (void)ws_size;
    const float* X   = (const float*)d_in[0];
    const float* G   = (const float*)d_in[1];
    const float* W1  = (const float*)d_in[2];
    const float* b1  = (const float*)d_in[3];
    const float* W2  = (const float*)d_in[4];
    const float* b2  = (const float*)d_in[5];
    const float* Wm1 = (const float*)d_in[6];
    const float* bm1 = (const float*)d_in[7];
    const float* Wm2 = (const float*)d_in[8];
    const float* bm2 = (const float*)d_in[9];
    float* out = (float*)d_out;

    char* ws = (char*)d_ws;
    u16* Gh   = (u16*)(ws);                     // 33554432 B
    u16* Gl   = (u16*)(ws + 33554432u);         // 33554432 B
    u16* W1th = (u16*)(ws + 67108864u);         // 131072 B
    u16* W1tl = (u16*)(ws + 67239936u);
    u16* W2th = (u16*)(ws + 67371008u);
    u16* W2tl = (u16*)(ws + 67502080u);
    u16* Tth  = (u16*)(ws + 67633152u);         // 16777216 B
    u16* Ttl  = (u16*)(ws + 84410368u);         // 16777216 B
    u16* XHh  = (u16*)(ws + 101187584u);        // 16777216 B  (X-split, then H)
    u16* XHl  = (u16*)(ws + 117964800u);        // 16777216 B  (total 134742016 B)

    // split G and X (fused), split+transpose W1/W2 (fused)
    splitGX_k<<<3072, 256, 0, stream>>>(G, Gh, Gl, X, XHh, XHl);
    splitT2_k<<<dim3(256, 2), 256, 0, stream>>>(W1, W1th, W1tl, W2, W2th, W2tl);

    // conv1 pre-prop: T1t = (X @ W1 + b1)^T, split
    gemm_small_k<<<dim3(2, 256), 256, 0, stream>>>(W1th, W1tl, XHh, XHl, b1, Tth, Ttl);
    // conv1 prop: H1 = relu(G @ T1), written split (overwrites X buffers)
    gemm_big_k<<<dim3(16, 2, 8), 512, 147456, stream>>>(Gh, Gl, Tth, Ttl, XHh, XHl);
    // conv2 pre-prop: T2t = (H1 @ W2 + b2)^T, split
    gemm_small_k<<<dim3(2, 256), 256, 0, stream>>>(W2th, W2tl, XHh, XHl, b2, Tth, Ttl);
    // conv2 prop: H2 = relu(G @ T2), written split
    gemm_big_k<<<dim3(16, 2, 8), 512, 147456, stream>>>(Gh, Gl, Tth, Ttl, XHh, XHl);
    // final MLP
    mlp_k<<<2048, 256, 0, stream>>>(XHh, XHl, Wm1, bm1, Wm2, bm2, out);
}

// Round 7
// 360.168 us; speedup vs baseline: 1.4018x; 1.2797x over previous
//
#include <hip/hip_runtime.h>

// Problem constants
#define N_NODES 4096
#define C_IN    256
#define HID     256
#define BATCH   8
#define R_TOT   32768   // BATCH * N_NODES

typedef unsigned short u16;
typedef short s8v  __attribute__((ext_vector_type(8)));   // 8 bf16 (bit pattern in shorts)
typedef float f4v  __attribute__((ext_vector_type(4)));
typedef u16   u16x4 __attribute__((ext_vector_type(4)));

#define MFMA(a,b,c) __builtin_amdgcn_mfma_f32_16x16x32_bf16((a),(b),(c),0,0,0)

__device__ __forceinline__ u16 bf_rne(float x) {
    unsigned u = __float_as_uint(x);
    u += 0x7fffu + ((u >> 16) & 1u);
    return (u16)(u >> 16);
}
__device__ __forceinline__ float bf_f(u16 h) {
    return __uint_as_float(((unsigned)h) << 16);
}
// fp32 -> bf16 hi/lo split: x ~= hi + lo, |err| <= 2^-18 |x|
__device__ __forceinline__ void split2f(float x, u16& h, u16& l) {
    h = bf_rne(x);
    l = bf_rne(x - bf_f(h));
}

// async global->LDS, 16B per lane. lds ptr must be wave-uniform (dest = base + lane*16)
__device__ __forceinline__ void glds16(const void* g, void* l) {
    __builtin_amdgcn_global_load_lds(
        (const __attribute__((address_space(1))) void*)g,
        (__attribute__((address_space(3))) void*)l, 16, 0, 0);
}

// ---------------- split kernels ----------------

// fused: G (4096x4096) -> hi only;  X (32768x256) -> hi/lo split. float4-vectorized.
__global__ void splitGX_k(const float* __restrict__ G, u16* __restrict__ Gh,
                          const float* __restrict__ X,
                          u16* __restrict__ Xh, u16* __restrict__ Xl) {
    const int nG = 4194304;              // 16M floats / 4
    const int nTot = nG + 2097152;       // + 8M floats / 4
    int i = blockIdx.x * blockDim.x + threadIdx.x;
    const int stride = gridDim.x * blockDim.x;
    for (; i < nTot; i += stride) {
        if (i < nG) {
            float4 x = ((const float4*)G)[i];
            u16x4 hh;
            hh[0] = bf_rne(x.x); hh[1] = bf_rne(x.y);
            hh[2] = bf_rne(x.z); hh[3] = bf_rne(x.w);
            ((u16x4*)Gh)[i] = hh;
        } else {
            const int j = i - nG;
            float4 x = ((const float4*)X)[j];
            u16x4 hh, ll; u16 a, b;
            split2f(x.x, a, b); hh[0] = a; ll[0] = b;
            split2f(x.y, a, b); hh[1] = a; ll[1] = b;
            split2f(x.z, a, b); hh[2] = a; ll[2] = b;
            split2f(x.w, a, b); hh[3] = a; ll[3] = b;
            ((u16x4*)Xh)[j] = hh; ((u16x4*)Xl)[j] = ll;
        }
    }
}

// transpose + split for both 256x256 weight matrices: out[h][c] = in[c][h]
__global__ void splitT2_k(const float* __restrict__ W1, u16* __restrict__ W1th,
                          u16* __restrict__ W1tl, const float* __restrict__ W2,
                          u16* __restrict__ W2th, u16* __restrict__ W2tl) {
    const float* in = blockIdx.y ? W2 : W1;
    u16* oh = blockIdx.y ? W2th : W1th;
    u16* ol = blockIdx.y ? W2tl : W1tl;
    const int c = blockIdx.x;      // row of in
    const int h = threadIdx.x;     // col of in
    float v = in[c * 256 + h];
    u16 hi, lo; split2f(v, hi, lo);
    oh[h * 256 + c] = hi;
    ol[h * 256 + c] = lo;
}

// ---------------- small GEMM: T[i=hid'][j=r] = sum_k Wt[i][k] * B[j][k] + bias[i] ----------------
// A (Wt) and B both pre-split bf16, all four tiles staged via glds16 (pre-swizzled source).
// Output written split hi/lo, transposed layout [256][32768]. No relu. bf16x3.
__global__ __launch_bounds__(256, 2) void gemm_small_k(
    const u16* __restrict__ Ah, const u16* __restrict__ Al,
    const u16* __restrict__ Bh, const u16* __restrict__ Bl,
    const float* __restrict__ bias,
    u16* __restrict__ Oh, u16* __restrict__ Ol)
{
    __shared__ u16 sAh[4096], sAl[4096], sBh[4096], sBl[4096];  // 128x32 each
    const int tid = threadIdx.x;
    const int w = tid >> 6, lane = tid & 63;
    const int i0 = blockIdx.x * 128;   // output row tile (hid')
    const int r0 = blockIdx.y * 128;   // output col tile (r)
    const int lr = lane & 15, lk = lane >> 4;
    const int wr = (w >> 1) * 64, wc = (w & 1) * 64;
    const int kslot = (lk ^ ((lr >> 1) & 3)) * 8;   // swizzled read slot (u16 units)
    const int cb = ((lane & 3) ^ ((lane >> 3) & 3)) * 8;  // pre-swizzled source slot

    const u16 *pAh[2], *pAl[2], *pBh[2], *pBl[2];
#pragma unroll
    for (int j = 0; j < 2; ++j) {
        const int ra = i0 + (w * 2 + j) * 16 + (lane >> 2);
        pAh[j] = Ah + (size_t)ra * 256 + cb;
        pAl[j] = Al + (size_t)ra * 256 + cb;
        const int rb = r0 + (w * 2 + j) * 16 + (lane >> 2);
        pBh[j] = Bh + (size_t)rb * 256 + cb;
        pBl[j] = Bl + (size_t)rb * 256 + cb;
    }

    f4v acc[4][4] = {};

    for (int kt = 0; kt < 8; ++kt) {
#pragma unroll
        for (int j = 0; j < 2; ++j) {
            glds16(pAh[j] + kt * 32, sAh + (w * 2 + j) * 512);
            glds16(pAl[j] + kt * 32, sAl + (w * 2 + j) * 512);
            glds16(pBh[j] + kt * 32, sBh + (w * 2 + j) * 512);
            glds16(pBl[j] + kt * 32, sBl + (w * 2 + j) * 512);
        }
        __syncthreads();

        s8v fah[4], fal[4], fbh[4], fbl[4];
#pragma unroll
        for (int m = 0; m < 4; ++m) {
            fah[m] = *(const s8v*)(sAh + (wr + m * 16 + lr) * 32 + kslot);
            fal[m] = *(const s8v*)(sAl + (wr + m * 16 + lr) * 32 + kslot);
            fbh[m] = *(const s8v*)(sBh + (wc + m * 16 + lr) * 32 + kslot);
            fbl[m] = *(const s8v*)(sBl + (wc + m * 16 + lr) * 32 + kslot);
        }
#pragma unroll
        for (int m = 0; m < 4; ++m)
#pragma unroll
            for (int n = 0; n < 4; ++n)
                acc[m][n] = MFMA(fah[m], fbh[n], acc[m][n]);
#pragma unroll
        for (int m = 0; m < 4; ++m)
#pragma unroll
            for (int n = 0; n < 4; ++n)
                acc[m][n] = MFMA(fah[m], fbl[n], acc[m][n]);
#pragma unroll
        for (int m = 0; m < 4; ++m)
#pragma unroll
            for (int n = 0; n < 4; ++n)
                acc[m][n] = MFMA(fal[m], fbh[n], acc[m][n]);
        __syncthreads();
    }

    // epilogue: +bias, split, store transposed output [hid'][32768]
#pragma unroll
    for (int m = 0; m < 4; ++m) {
#pragma unroll
        for (int q = 0; q < 4; ++q) {
            const int rowg = i0 + wr + m * 16 + lk * 4 + q;
            const float bv = bias[rowg];
#pragma unroll
            for (int n = 0; n < 4; ++n) {
                const int colg = r0 + wc + n * 16 + lr;
                float v = acc[m][n][q] + bv;
                u16 hi, lo; split2f(v, hi, lo);
                const size_t off = (size_t)rowg * R_TOT + colg;
                Oh[off] = hi; Ol[off] = lo;
            }
        }
    }
}

// ---------------- big GEMM: H[b][i=n][j=h] = relu( sum_m Ghi[i][m] * (Th+Tl)[j][b*4096+m] ) ----------------
// bf16x2: A = G bf16-hi only; B = T split hi/lo. BM=256 BN=128 BK=32, 8 waves (4Mx2N),
// triple-buffered LDS (3 x 32KB), 3 phases/K-tile {8 hh | 8 hh | 16 hl}, counted vmcnt(4),
// setprio around MFMA clusters, 16x16x32 MFMA. Output written split hi/lo bf16.
// Buffer layout (u16): [A-hi 256x32 | B-hi 128x32 | B-lo 128x32] = 16384 u16 = 32KB.
__global__ __launch_bounds__(512, 2) void gemm_big_k(
    const u16* __restrict__ Gh,
    const u16* __restrict__ Th, const u16* __restrict__ Tl,
    u16* __restrict__ Hh, u16* __restrict__ Hl)
{
    extern __shared__ u16 lds[];   // 3 * 16384 u16 = 98304 B
    const int tid = threadIdx.x;
    const int w = tid >> 6, l = tid & 63;
    const int n0 = blockIdx.x * 256;
    const int h0 = blockIdx.y * 128;
    const int b  = blockIdx.z;
    const int lr = l & 15, lk = l >> 4;
    const int kslot8 = (lk ^ ((lr >> 1) & 3)) * 8;  // swizzled read slot (u16)
    const int wm = w >> 1, wn = w & 1;

    const int cb = ((l & 3) ^ ((l >> 3) & 3)) * 8;  // pre-swizzled source slot
    const u16* pAh0 = Gh + (size_t)(n0 + 16 * w + (l >> 2)) * 4096 + cb;
    const u16* pAh1 = pAh0 + 128 * 4096;
    const u16* pBh  = Th + (size_t)(h0 + (tid >> 2)) * R_TOT + (size_t)b * 4096 + cb;
    const u16* pBl  = Tl + (size_t)(h0 + (tid >> 2)) * R_TOT + (size_t)b * 4096 + cb;

    // wave-uniform LDS stage bases (u16 units)
    const int aw0 = (16 * w) * 32;   // A rows 16w..16w+15 (j=1 adds 4096); also B chunk base

    f4v acc[4][4] = {};

#define STAGE4(STG) do {                                                       \
    u16* Ls = lds + (STG) * 16384;                                             \
    glds16(pAh0, Ls + aw0);                                                    \
    glds16(pAh1, Ls + aw0 + 4096);                                             \
    glds16(pBh,  Ls + 8192 + aw0);                                             \
    glds16(pBl,  Ls + 12288 + aw0);                                            \
    pAh0 += 32; pAh1 += 32; pBh += 32; pBl += 32;                              \
} while (0)

// One K-tile: 3 phases. VMODE: 0 = vmcnt(4) (steady), 1 = vmcnt(0) (drain), 2 = skip.
#define KTILE(CUR, STG, DO_STAGE, VMODE) do {                                  \
    const u16* Lc = lds + (CUR) * 16384;                                       \
    u16* Ls = lds + (STG) * 16384;                                             \
    s8v fah[4], fbh[4], fbl[4];                                                \
    /* P0: read A-hi + B-hi, stage A-hi pair */                                \
    _Pragma("unroll") for (int m = 0; m < 4; ++m)                              \
        fah[m] = *(const s8v*)(Lc + (wm * 64 + m * 16 + lr) * 32 + kslot8);    \
    _Pragma("unroll") for (int n = 0; n < 4; ++n)                              \
        fbh[n] = *(const s8v*)(Lc + 8192 + (wn * 64 + n * 16 + lr) * 32 + kslot8); \
    if (DO_STAGE) { glds16(pAh0, Ls + aw0); glds16(pAh1, Ls + aw0 + 4096); }   \
    __builtin_amdgcn_s_barrier();                                              \
    __builtin_amdgcn_s_setprio(1);                                             \
    _Pragma("unroll") for (int m = 0; m < 2; ++m)                              \
        _Pragma("unroll") for (int n = 0; n < 4; ++n)                          \
            acc[m][n] = MFMA(fah[m], fbh[n], acc[m][n]);                       \
    __builtin_amdgcn_s_setprio(0);                                             \
    __builtin_amdgcn_s_barrier();                                              \
    /* P1: read B-lo, stage B pair, advance ptrs */                            \
    _Pragma("unroll") for (int n = 0; n < 4; ++n)                              \
        fbl[n] = *(const s8v*)(Lc + 12288 + (wn * 64 + n * 16 + lr) * 32 + kslot8); \
    if (DO_STAGE) { glds16(pBh, Ls + 8192 + aw0); glds16(pBl, Ls + 12288 + aw0); \
        pAh0 += 32; pAh1 += 32; pBh += 32; pBl += 32; }                        \
    __builtin_amdgcn_s_barrier();                                              \
    __builtin_amdgcn_s_setprio(1);                                             \
    _Pragma("unroll") for (int m = 2; m < 4; ++m)                              \
        _Pragma("unroll") for (int n = 0; n < 4; ++n)                          \
            acc[m][n] = MFMA(fah[m], fbh[n], acc[m][n]);                       \
    __builtin_amdgcn_s_setprio(0);                                             \
    __builtin_amdgcn_s_barrier();                                              \
    /* P2: Ah*Bl (16), tile-end wait */                                        \
    __builtin_amdgcn_s_setprio(1);                                             \
    _Pragma("unroll") for (int m = 0; m < 4; ++m)                              \
        _Pragma("unroll") for (int n = 0; n < 4; ++n)                          \
            acc[m][n] = MFMA(fah[m], fbl[n], acc[m][n]);                       \
    __builtin_amdgcn_s_setprio(0);                                             \
    if (VMODE == 0)      asm volatile("s_waitcnt vmcnt(4)" ::: "memory");      \
    else if (VMODE == 1) asm volatile("s_waitcnt vmcnt(0)" ::: "memory");      \
    if (VMODE != 2) __builtin_amdgcn_s_barrier();                              \
    __builtin_amdgcn_sched_barrier(0);                                         \
} while (0)

    // prologue: stage tiles 0 (buf0) and 1 (buf1)
    STAGE4(0);
    STAGE4(1);
    asm volatile("s_waitcnt vmcnt(4)" ::: "memory");   // tile-0 loads landed
    __builtin_amdgcn_s_barrier();
    __builtin_amdgcn_sched_barrier(0);

    // main loop: tiles 0..125 (42 x 3), tile t in buf t%3, staging t+2 into (t+2)%3
    for (int it = 0; it < 42; ++it) {
        KTILE(0, 2, 1, 0);
        KTILE(1, 0, 1, 0);
        KTILE(2, 1, 1, 0);
    }
    KTILE(0, 2, 0, 1);   // tile 126: drain tile-127 loads
    KTILE(1, 0, 0, 2);   // tile 127: nothing outstanding

#undef STAGE4
#undef KTILE

    // epilogue: relu, split, store H as hi/lo bf16 [b*4096+row][col]
    const size_t obase = ((size_t)b * 4096 + n0 + wm * 64 + lk * 4) * 256
                       + h0 + wn * 64 + lr;
#pragma unroll
    for (int m = 0; m < 4; ++m)
#pragma unroll
        for (int n = 0; n < 4; ++n)
#pragma unroll
            for (int q = 0; q < 4; ++q) {
                float v = acc[m][n][q];
                v = v > 0.f ? v : 0.f;
                u16 hi, lo; split2f(v, hi, lo);
                const size_t off = obase + (size_t)(m * 16 + q) * 256 + n * 16;
                Hh[off] = hi; Hl[off] = lo;
            }
}

// ---------------- final MLP: out[r] = relu(H[r,:] @ Wm1 + bm1) @ Wm2 + bm2 ----------------
__global__ __launch_bounds__(256) void mlp_k(
    const u16* __restrict__ Hh, const u16* __restrict__ Hl,
    const float* __restrict__ Wm1, const float* __restrict__ bm1,
    const float* __restrict__ Wm2, const float* __restrict__ bm2,
    float* __restrict__ out)
{
    __shared__ float rb[4][256];
    const int w = threadIdx.x >> 6, lane = threadIdx.x & 63;
    const int gw0 = blockIdx.x * 4 + w;
    const int stride = gridDim.x * 4;
    for (int r = gw0; r < R_TOT; r += stride) {
        u16x4 hh = *(const u16x4*)(Hh + (size_t)r * 256 + lane * 4);
        u16x4 ll = *(const u16x4*)(Hl + (size_t)r * 256 + lane * 4);
#pragma unroll
        for (int j = 0; j < 4; ++j)
            rb[w][lane * 4 + j] = bf_f(hh[j]) + bf_f(ll[j]);
        __syncthreads();
        float acc = 0.f;
#pragma unroll 8
        for (int k = 0; k < 256; ++k)
            acc = fmaf(rb[w][k], Wm1[k * 64 + lane], acc);
        float m = acc + bm1[lane];
        m = m > 0.f ? m : 0.f;
        float s = m * Wm2[lane];
#pragma unroll
        for (int off = 32; off; off >>= 1) s += __shfl_down(s, off);
        if (lane == 0) out[r] = s + bm2[0];
        __syncthreads();
    }
}

// ---------------- launch ----------------
extern "C" void kernel_launch(void* const* d_in, const int* in_sizes, int n_in,
                              void* d_out, int out_size, void* d_ws, size_t ws_size,
                              hipStream_t stream) {
    (void)in_sizes; (void)n_in; (void)out_size; (void)ws_size;
    const float* X   = (const float*)d_in[0];
    const float* G   = (const float*)d_in[1];
    const float* W1  = (const float*)d_in[2];
    const float* b1  = (const float*)d_in[3];
    const float* W2  = (const float*)d_in[4];
    const float* b2  = (const float*)d_in[5];
    const float* Wm1 = (const float*)d_in[6];
    const float* bm1 = (const float*)d_in[7];
    const float* Wm2 = (const float*)d_in[8];
    const float* bm2 = (const float*)d_in[9];
    float* out = (float*)d_out;

    char* ws = (char*)d_ws;
    u16* Gh   = (u16*)(ws);                     // 33554432 B (hi only; lo slot unused)
    u16* W1th = (u16*)(ws + 67108864u);         // 131072 B
    u16* W1tl = (u16*)(ws + 67239936u);
    u16* W2th = (u16*)(ws + 67371008u);
    u16* W2tl = (u16*)(ws + 67502080u);
    u16* Tth  = (u16*)(ws + 67633152u);         // 16777216 B
    u16* Ttl  = (u16*)(ws + 84410368u);         // 16777216 B
    u16* XHh  = (u16*)(ws + 101187584u);        // 16777216 B  (X-split, then H)
    u16* XHl  = (u16*)(ws + 117964800u);        // 16777216 B  (total 134742016 B)

    // split G (hi only) and X (hi/lo), fused; split+transpose W1/W2, fused
    splitGX_k<<<3072, 256, 0, stream>>>(G, Gh, X, XHh, XHl);
    splitT2_k<<<dim3(256, 2), 256, 0, stream>>>(W1, W1th, W1tl, W2, W2th, W2tl);

    // conv1 pre-prop: T1t = (X @ W1 + b1)^T, split
    gemm_small_k<<<dim3(2, 256), 256, 0, stream>>>(W1th, W1tl, XHh, XHl, b1, Tth, Ttl);
    // conv1 prop: H1 = relu(G @ T1), written split (overwrites X buffers)
    gemm_big_k<<<dim3(16, 2, 8), 512, 98304, stream>>>(Gh, Tth, Ttl, XHh, XHl);
    // conv2 pre-prop: T2t = (H1 @ W2 + b2)^T, split
    gemm_small_k<<<dim3(2, 256), 256, 0, stream>>>(W2th, W2tl, XHh, XHl, b2, Tth, Ttl);
    // conv2 prop: H2 = relu(G @ T2), written split
    gemm_big_k<<<dim3(16, 2, 8), 512, 98304, stream>>>(Gh, Tth, Ttl, XHh, XHl);
    // final MLP
    mlp_k<<<2048, 256, 0, stream>>>(XHh, XHl, Wm1, bm1, Wm2, bm2, out);
}

// Round 8
// 263.287 us; speedup vs baseline: 1.9176x; 1.3680x over previous
//
#include <hip/hip_runtime.h>

// Problem constants
#define N_NODES 4096
#define C_IN    256
#define HID     256
#define BATCH   8
#define R_TOT   32768   // BATCH * N_NODES

typedef unsigned short u16;
typedef short s8v  __attribute__((ext_vector_type(8)));   // 8 bf16 (bit pattern in shorts)
typedef float f4v  __attribute__((ext_vector_type(4)));
typedef u16   u16x4 __attribute__((ext_vector_type(4)));

#define MFMA(a,b,c) __builtin_amdgcn_mfma_f32_16x16x32_bf16((a),(b),(c),0,0,0)

__device__ __forceinline__ u16 bf_rne(float x) {
    unsigned u = __float_as_uint(x);
    u += 0x7fffu + ((u >> 16) & 1u);
    return (u16)(u >> 16);
}
__device__ __forceinline__ float bf_f(u16 h) {
    return __uint_as_float(((unsigned)h) << 16);
}
// fp32 -> bf16 hi/lo split: x ~= hi + lo, |err| <= 2^-18 |x|
__device__ __forceinline__ void split2f(float x, u16& h, u16& l) {
    h = bf_rne(x);
    l = bf_rne(x - bf_f(h));
}

// async global->LDS, 16B per lane. lds ptr must be wave-uniform (dest = base + lane*16)
__device__ __forceinline__ void glds16(const void* g, void* l) {
    __builtin_amdgcn_global_load_lds(
        (const __attribute__((address_space(1))) void*)g,
        (__attribute__((address_space(3))) void*)l, 16, 0, 0);
}

// ---------------- split kernels ----------------

// fused: G (4096x4096) -> hi only;  X (32768x256) -> hi/lo split. float4-vectorized.
__global__ void splitGX_k(const float* __restrict__ G, u16* __restrict__ Gh,
                          const float* __restrict__ X,
                          u16* __restrict__ Xh, u16* __restrict__ Xl) {
    const int nG = 4194304;              // 16M floats / 4
    const int nTot = nG + 2097152;       // + 8M floats / 4
    int i = blockIdx.x * blockDim.x + threadIdx.x;
    const int stride = gridDim.x * blockDim.x;
    for (; i < nTot; i += stride) {
        if (i < nG) {
            float4 x = ((const float4*)G)[i];
            u16x4 hh;
            hh[0] = bf_rne(x.x); hh[1] = bf_rne(x.y);
            hh[2] = bf_rne(x.z); hh[3] = bf_rne(x.w);
            ((u16x4*)Gh)[i] = hh;
        } else {
            const int j = i - nG;
            float4 x = ((const float4*)X)[j];
            u16x4 hh, ll; u16 a, b;
            split2f(x.x, a, b); hh[0] = a; ll[0] = b;
            split2f(x.y, a, b); hh[1] = a; ll[1] = b;
            split2f(x.z, a, b); hh[2] = a; ll[2] = b;
            split2f(x.w, a, b); hh[3] = a; ll[3] = b;
            ((u16x4*)Xh)[j] = hh; ((u16x4*)Xl)[j] = ll;
        }
    }
}

// transpose + split for both 256x256 weight matrices: out[h][c] = in[c][h]
__global__ void splitT2_k(const float* __restrict__ W1, u16* __restrict__ W1th,
                          u16* __restrict__ W1tl, const float* __restrict__ W2,
                          u16* __restrict__ W2th, u16* __restrict__ W2tl) {
    const float* in = blockIdx.y ? W2 : W1;
    u16* oh = blockIdx.y ? W2th : W1th;
    u16* ol = blockIdx.y ? W2tl : W1tl;
    const int c = blockIdx.x;      // row of in
    const int h = threadIdx.x;     // col of in
    float v = in[c * 256 + h];
    u16 hi, lo; split2f(v, hi, lo);
    oh[h * 256 + c] = hi;
    ol[h * 256 + c] = lo;
}

// ---------------- small GEMM: T[i=hid'][j=r] = sum_k Wt[i][k] * B[j][k] + bias[i] ----------------
// A (Wt) and B both pre-split bf16, staged via glds16 (pre-swizzled source). Internal bf16x3.
// Output: bf16-hi ONLY (consumer is the x1 big GEMM), transposed layout [256][32768].
__global__ __launch_bounds__(256, 2) void gemm_small_k(
    const u16* __restrict__ Ah, const u16* __restrict__ Al,
    const u16* __restrict__ Bh, const u16* __restrict__ Bl,
    const float* __restrict__ bias, u16* __restrict__ Oh)
{
    __shared__ u16 sAh[4096], sAl[4096], sBh[4096], sBl[4096];  // 128x32 each
    const int tid = threadIdx.x;
    const int w = tid >> 6, lane = tid & 63;
    const int i0 = blockIdx.x * 128;   // output row tile (hid')
    const int r0 = blockIdx.y * 128;   // output col tile (r)
    const int lr = lane & 15, lk = lane >> 4;
    const int wr = (w >> 1) * 64, wc = (w & 1) * 64;
    const int kslot = (lk ^ ((lr >> 1) & 3)) * 8;   // swizzled read slot (u16 units)
    const int cb = ((lane & 3) ^ ((lane >> 3) & 3)) * 8;  // pre-swizzled source slot

    const u16 *pAh[2], *pAl[2], *pBh[2], *pBl[2];
#pragma unroll
    for (int j = 0; j < 2; ++j) {
        const int ra = i0 + (w * 2 + j) * 16 + (lane >> 2);
        pAh[j] = Ah + (size_t)ra * 256 + cb;
        pAl[j] = Al + (size_t)ra * 256 + cb;
        const int rb = r0 + (w * 2 + j) * 16 + (lane >> 2);
        pBh[j] = Bh + (size_t)rb * 256 + cb;
        pBl[j] = Bl + (size_t)rb * 256 + cb;
    }

    f4v acc[4][4] = {};

    for (int kt = 0; kt < 8; ++kt) {
#pragma unroll
        for (int j = 0; j < 2; ++j) {
            glds16(pAh[j] + kt * 32, sAh + (w * 2 + j) * 512);
            glds16(pAl[j] + kt * 32, sAl + (w * 2 + j) * 512);
            glds16(pBh[j] + kt * 32, sBh + (w * 2 + j) * 512);
            glds16(pBl[j] + kt * 32, sBl + (w * 2 + j) * 512);
        }
        __syncthreads();

        s8v fah[4], fal[4], fbh[4], fbl[4];
#pragma unroll
        for (int m = 0; m < 4; ++m) {
            fah[m] = *(const s8v*)(sAh + (wr + m * 16 + lr) * 32 + kslot);
            fal[m] = *(const s8v*)(sAl + (wr + m * 16 + lr) * 32 + kslot);
            fbh[m] = *(const s8v*)(sBh + (wc + m * 16 + lr) * 32 + kslot);
            fbl[m] = *(const s8v*)(sBl + (wc + m * 16 + lr) * 32 + kslot);
        }
#pragma unroll
        for (int m = 0; m < 4; ++m)
#pragma unroll
            for (int n = 0; n < 4; ++n)
                acc[m][n] = MFMA(fah[m], fbh[n], acc[m][n]);
#pragma unroll
        for (int m = 0; m < 4; ++m)
#pragma unroll
            for (int n = 0; n < 4; ++n)
                acc[m][n] = MFMA(fah[m], fbl[n], acc[m][n]);
#pragma unroll
        for (int m = 0; m < 4; ++m)
#pragma unroll
            for (int n = 0; n < 4; ++n)
                acc[m][n] = MFMA(fal[m], fbh[n], acc[m][n]);
        __syncthreads();
    }

    // epilogue: +bias, round to bf16-hi, store transposed output [hid'][32768]
#pragma unroll
    for (int m = 0; m < 4; ++m) {
#pragma unroll
        for (int q = 0; q < 4; ++q) {
            const int rowg = i0 + wr + m * 16 + lk * 4 + q;
            const float bv = bias[rowg];
#pragma unroll
            for (int n = 0; n < 4; ++n) {
                const int colg = r0 + wc + n * 16 + lr;
                float v = acc[m][n][q] + bv;
                Oh[(size_t)rowg * R_TOT + colg] = bf_rne(v);
            }
        }
    }
}

// ---------------- big GEMM: H[b][i=n][j=h] = relu( sum_m Ghi[i][m] * Thi[j][b*4096+m] ) ----------------
// Pure bf16 (x1). BM=256 BN=128 BK=64, 8 waves (4Mx2N, per-wave 64x64), triple-buffered
// LDS (3 x 48KB), 2 phases/K-tile (ks0 | ks1), counted vmcnt(6), setprio around MFMA.
// Row = 64 u16 = 128B; swizzle: slot s' = (ks*4+lk) ^ (row&7)  (8 slots x 16B, uniform banks).
// Staging: per-wave 1KB chunks (8 rows x 64 u16), source pre-swizzled by (l&7)^(l>>3).
// Buffer layout (u16): [A 256x64 | B 128x64] = 24576 u16 = 48KB.
__global__ __launch_bounds__(512, 2) void gemm_big_k(
    const u16* __restrict__ Gh, const u16* __restrict__ Th,
    u16* __restrict__ Hh, u16* __restrict__ Hl)
{
    extern __shared__ u16 lds[];   // 3 * 24576 u16 = 147456 B
    const int tid = threadIdx.x;
    const int w = tid >> 6, l = tid & 63;
    const int n0 = blockIdx.x * 256;
    const int h0 = blockIdx.y * 128;
    const int b  = blockIdx.z;
    const int lr = l & 15, lk = l >> 4;
    const int wm = w >> 1, wn = w & 1;
    // fragment read slots (u16 units): s' = (ks*4+lk) ^ (lr&7)
    const int sl0 = ((lk)     ^ (lr & 7)) * 8;
    const int sl1 = ((4 + lk) ^ (lr & 7)) * 8;

    // staging: per-lane source swizzle (chunk = 8 rows x 64 u16)
    const int srow  = l >> 3;                   // row within chunk
    const int sslot = ((l & 7) ^ srow) * 8;     // source col slot (u16)

    // A chunks c = w, w+8, w+16, w+24 (rows 8c..8c+7); B chunks c = w, w+8
    const u16* pA0 = Gh + (size_t)(n0 + 8 * w        + srow) * 4096 + sslot;
    const u16* pA1 = Gh + (size_t)(n0 + 8 * (w + 8)  + srow) * 4096 + sslot;
    const u16* pA2 = Gh + (size_t)(n0 + 8 * (w + 16) + srow) * 4096 + sslot;
    const u16* pA3 = Gh + (size_t)(n0 + 8 * (w + 24) + srow) * 4096 + sslot;
    const u16* pB0 = Th + (size_t)(h0 + 8 * w       + srow) * R_TOT + (size_t)b * 4096 + sslot;
    const u16* pB1 = Th + (size_t)(h0 + 8 * (w + 8) + srow) * R_TOT + (size_t)b * 4096 + sslot;

    // wave-uniform LDS chunk bases (u16)
    const int dA0 = w * 512, dA1 = (w + 8) * 512, dA2 = (w + 16) * 512, dA3 = (w + 24) * 512;
    const int dB0 = 16384 + w * 512, dB1 = 16384 + (w + 8) * 512;

    f4v acc[4][4] = {};

#define STAGE6(STG) do {                                                       \
    u16* Ls = lds + (STG) * 24576;                                             \
    glds16(pA0, Ls + dA0); glds16(pA1, Ls + dA1);                              \
    glds16(pA2, Ls + dA2); glds16(pA3, Ls + dA3);                              \
    glds16(pB0, Ls + dB0); glds16(pB1, Ls + dB1);                              \
    pA0 += 64; pA1 += 64; pA2 += 64; pA3 += 64; pB0 += 64; pB1 += 64;          \
} while (0)

// One K-tile: 2 phases. VMODE: 0 = vmcnt(6) (steady), 1 = vmcnt(0) (drain), 2 = skip.
#define KTILE(CUR, STG, DO_STAGE, VMODE) do {                                  \
    const u16* Lc = lds + (CUR) * 24576;                                       \
    u16* Ls = lds + (STG) * 24576;                                             \
    /* P0: ks0 fragments; stage first 3 chunks */                              \
    { s8v fa[4], fb[4];                                                        \
      _Pragma("unroll") for (int m = 0; m < 4; ++m)                            \
          fa[m] = *(const s8v*)(Lc + (wm * 64 + m * 16 + lr) * 64 + sl0);      \
      _Pragma("unroll") for (int n = 0; n < 4; ++n)                            \
          fb[n] = *(const s8v*)(Lc + 16384 + (wn * 64 + n * 16 + lr) * 64 + sl0); \
      if (DO_STAGE) { glds16(pA0, Ls + dA0); glds16(pA1, Ls + dA1);            \
                      glds16(pB0, Ls + dB0); }                                 \
      __builtin_amdgcn_s_barrier();                                            \
      __builtin_amdgcn_s_setprio(1);                                           \
      _Pragma("unroll") for (int m = 0; m < 4; ++m)                            \
          _Pragma("unroll") for (int n = 0; n < 4; ++n)                        \
              acc[m][n] = MFMA(fa[m], fb[n], acc[m][n]);                       \
      __builtin_amdgcn_s_setprio(0);                                           \
      __builtin_amdgcn_s_barrier(); }                                          \
    /* P1: ks1 fragments; stage last 3 chunks, advance ptrs */                 \
    { s8v fa[4], fb[4];                                                        \
      _Pragma("unroll") for (int m = 0; m < 4; ++m)                            \
          fa[m] = *(const s8v*)(Lc + (wm * 64 + m * 16 + lr) * 64 + sl1);      \
      _Pragma("unroll") for (int n = 0; n < 4; ++n)                            \
          fb[n] = *(const s8v*)(Lc + 16384 + (wn * 64 + n * 16 + lr) * 64 + sl1); \
      if (DO_STAGE) { glds16(pA2, Ls + dA2); glds16(pA3, Ls + dA3);            \
                      glds16(pB1, Ls + dB1);                                   \
                      pA0 += 64; pA1 += 64; pA2 += 64; pA3 += 64;              \
                      pB0 += 64; pB1 += 64; }                                  \
      __builtin_amdgcn_s_barrier();                                            \
      __builtin_amdgcn_s_setprio(1);                                           \
      _Pragma("unroll") for (int m = 0; m < 4; ++m)                            \
          _Pragma("unroll") for (int n = 0; n < 4; ++n)                        \
              acc[m][n] = MFMA(fa[m], fb[n], acc[m][n]);                       \
      __builtin_amdgcn_s_setprio(0); }                                         \
    if (VMODE == 0)      asm volatile("s_waitcnt vmcnt(6)" ::: "memory");      \
    else if (VMODE == 1) asm volatile("s_waitcnt vmcnt(0)" ::: "memory");      \
    if (VMODE != 2) __builtin_amdgcn_s_barrier();                              \
    __builtin_amdgcn_sched_barrier(0);                                         \
} while (0)

    // prologue: stage tiles 0 (buf0) and 1 (buf1); 12 loads in flight per wave
    STAGE6(0);
    STAGE6(1);
    asm volatile("s_waitcnt vmcnt(6)" ::: "memory");   // tile-0 loads landed
    __builtin_amdgcn_s_barrier();
    __builtin_amdgcn_sched_barrier(0);

    // 64 K-tiles: t in buf t%3, staging t+2 while computing t (t <= 61)
    for (int it = 0; it < 20; ++it) {
        KTILE(0, 2, 1, 0);
        KTILE(1, 0, 1, 0);
        KTILE(2, 1, 1, 0);
    }
    KTILE(0, 2, 1, 0);   // t=60, stages 62
    KTILE(1, 0, 1, 0);   // t=61, stages 63
    KTILE(2, 1, 0, 1);   // t=62, drain tile-63 loads
    KTILE(0, 2, 0, 2);   // t=63

#undef STAGE6
#undef KTILE

    // epilogue: relu, split, store H as hi/lo bf16 [b*4096+row][col]
    const size_t obase = ((size_t)b * 4096 + n0 + wm * 64 + lk * 4) * 256
                       + h0 + wn * 64 + lr;
#pragma unroll
    for (int m = 0; m < 4; ++m)
#pragma unroll
        for (int n = 0; n < 4; ++n)
#pragma unroll
            for (int q = 0; q < 4; ++q) {
                float v = acc[m][n][q];
                v = v > 0.f ? v : 0.f;
                u16 hi, lo; split2f(v, hi, lo);
                const size_t off = obase + (size_t)(m * 16 + q) * 256 + n * 16;
                Hh[off] = hi; Hl[off] = lo;
            }
}

// ---------------- final MLP: out[r] = relu(H[r,:] @ Wm1 + bm1) @ Wm2 + bm2 ----------------
__global__ __launch_bounds__(256) void mlp_k(
    const u16* __restrict__ Hh, const u16* __restrict__ Hl,
    const float* __restrict__ Wm1, const float* __restrict__ bm1,
    const float* __restrict__ Wm2, const float* __restrict__ bm2,
    float* __restrict__ out)
{
    __shared__ float rb[4][256];
    const int w = threadIdx.x >> 6, lane = threadIdx.x & 63;
    const int gw0 = blockIdx.x * 4 + w;
    const int stride = gridDim.x * 4;
    for (int r = gw0; r < R_TOT; r += stride) {
        u16x4 hh = *(const u16x4*)(Hh + (size_t)r * 256 + lane * 4);
        u16x4 ll = *(const u16x4*)(Hl + (size_t)r * 256 + lane * 4);
#pragma unroll
        for (int j = 0; j < 4; ++j)
            rb[w][lane * 4 + j] = bf_f(hh[j]) + bf_f(ll[j]);
        __syncthreads();
        float acc = 0.f;
#pragma unroll 8
        for (int k = 0; k < 256; ++k)
            acc = fmaf(rb[w][k], Wm1[k * 64 + lane], acc);
        float m = acc + bm1[lane];
        m = m > 0.f ? m : 0.f;
        float s = m * Wm2[lane];
#pragma unroll
        for (int off = 32; off; off >>= 1) s += __shfl_down(s, off);
        if (lane == 0) out[r] = s + bm2[0];
        __syncthreads();
    }
}

// ---------------- launch ----------------
extern "C" void kernel_launch(void* const* d_in, const int* in_sizes, int n_in,
                              void* d_out, int out_size, void* d_ws, size_t ws_size,
                              hipStream_t stream) {
    (void)in_sizes; (void)n_in; (void)out_size; (void)ws_size;
    const float* X   = (const float*)d_in[0];
    const float* G   = (const float*)d_in[1];
    const float* W1  = (const float*)d_in[2];
    const float* b1  = (const float*)d_in[3];
    const float* W2  = (const float*)d_in[4];
    const float* b2  = (const float*)d_in[5];
    const float* Wm1 = (const float*)d_in[6];
    const float* bm1 = (const float*)d_in[7];
    const float* Wm2 = (const float*)d_in[8];
    const float* bm2 = (const float*)d_in[9];
    float* out = (float*)d_out;

    char* ws = (char*)d_ws;
    u16* Gh   = (u16*)(ws);                     // 33554432 B (hi only)
    u16* W1th = (u16*)(ws + 67108864u);         // 131072 B
    u16* W1tl = (u16*)(ws + 67239936u);
    u16* W2th = (u16*)(ws + 67371008u);
    u16* W2tl = (u16*)(ws + 67502080u);
    u16* Tth  = (u16*)(ws + 67633152u);         // 16777216 B (hi only; lo slot unused)
    u16* XHh  = (u16*)(ws + 101187584u);        // 16777216 B  (X-split, then H)
    u16* XHl  = (u16*)(ws + 117964800u);        // 16777216 B  (total 134742016 B)

    // split G (hi only) and X (hi/lo), fused; split+transpose W1/W2, fused
    splitGX_k<<<3072, 256, 0, stream>>>(G, Gh, X, XHh, XHl);
    splitT2_k<<<dim3(256, 2), 256, 0, stream>>>(W1, W1th, W1tl, W2, W2th, W2tl);

    // conv1 pre-prop: T1t = bf16((X @ W1 + b1)^T)
    gemm_small_k<<<dim3(2, 256), 256, 0, stream>>>(W1th, W1tl, XHh, XHl, b1, Tth);
    // conv1 prop: H1 = relu(G @ T1), written split (overwrites X buffers)
    gemm_big_k<<<dim3(16, 2, 8), 512, 147456, stream>>>(Gh, Tth, XHh, XHl);
    // conv2 pre-prop: T2t = bf16((H1 @ W2 + b2)^T)
    gemm_small_k<<<dim3(2, 256), 256, 0, stream>>>(W2th, W2tl, XHh, XHl, b2, Tth);
    // conv2 prop: H2 = relu(G @ T2), written split
    gemm_big_k<<<dim3(16, 2, 8), 512, 147456, stream>>>(Gh, Tth, XHh, XHl);
    // final MLP
    mlp_k<<<2048, 256, 0, stream>>>(XHh, XHl, Wm1, bm1, Wm2, bm2, out);
}

// Round 9
// 191.096 us; speedup vs baseline: 2.6421x; 1.3778x over previous
//
#include <hip/hip_runtime.h>

// Problem constants
#define N_NODES 4096
#define C_IN    256
#define HID     256
#define BATCH   8
#define R_TOT   32768   // BATCH * N_NODES

typedef unsigned short u16;
typedef short s8v  __attribute__((ext_vector_type(8)));   // 8 bf16 (bit pattern in shorts)
typedef float f4v  __attribute__((ext_vector_type(4)));
typedef u16   u16x4 __attribute__((ext_vector_type(4)));

#define MFMA(a,b,c) __builtin_amdgcn_mfma_f32_16x16x32_bf16((a),(b),(c),0,0,0)

__device__ __forceinline__ u16 bf_rne(float x) {
    unsigned u = __float_as_uint(x);
    u += 0x7fffu + ((u >> 16) & 1u);
    return (u16)(u >> 16);
}
__device__ __forceinline__ float bf_f(u16 h) {
    return __uint_as_float(((unsigned)h) << 16);
}
// fp32 -> bf16 hi/lo split: x ~= hi + lo, |err| <= 2^-18 |x|
__device__ __forceinline__ void split2f(float x, u16& h, u16& l) {
    h = bf_rne(x);
    l = bf_rne(x - bf_f(h));
}

// async global->LDS, 16B per lane. lds ptr must be wave-uniform (dest = base + lane*16)
__device__ __forceinline__ void glds16(const void* g, void* l) {
    __builtin_amdgcn_global_load_lds(
        (const __attribute__((address_space(1))) void*)g,
        (__attribute__((address_space(3))) void*)l, 16, 0, 0);
}

// ---------------- split kernels ----------------

// fused: G (4096x4096) -> bf16 hi;  X (32768x256) -> bf16 hi. float4-vectorized.
__global__ void splitGX_k(const float* __restrict__ G, u16* __restrict__ Gh,
                          const float* __restrict__ X, u16* __restrict__ Xh) {
    const int nG = 4194304;              // 16M floats / 4
    const int nTot = nG + 2097152;       // + 8M floats / 4
    int i = blockIdx.x * blockDim.x + threadIdx.x;
    const int stride = gridDim.x * blockDim.x;
    for (; i < nTot; i += stride) {
        const float4* src; u16x4* dst; int j;
        if (i < nG) { src = (const float4*)G; dst = (u16x4*)Gh; j = i; }
        else        { src = (const float4*)X; dst = (u16x4*)Xh; j = i - nG; }
        float4 x = src[j];
        u16x4 hh;
        hh[0] = bf_rne(x.x); hh[1] = bf_rne(x.y);
        hh[2] = bf_rne(x.z); hh[3] = bf_rne(x.w);
        dst[j] = hh;
    }
}

// transpose + split for both 256x256 weight matrices: out[h][c] = in[c][h]
__global__ void splitT2_k(const float* __restrict__ W1, u16* __restrict__ W1th,
                          u16* __restrict__ W1tl, const float* __restrict__ W2,
                          u16* __restrict__ W2th, u16* __restrict__ W2tl) {
    const float* in = blockIdx.y ? W2 : W1;
    u16* oh = blockIdx.y ? W2th : W1th;
    u16* ol = blockIdx.y ? W2tl : W1tl;
    const int c = blockIdx.x;      // row of in
    const int h = threadIdx.x;     // col of in
    float v = in[c * 256 + h];
    u16 hi, lo; split2f(v, hi, lo);
    oh[h * 256 + c] = hi;
    ol[h * 256 + c] = lo;
}

// ---------------- small GEMM: T[i=hid'][j=r] = sum_k Wt[i][k] * B[j][k] + bias[i] ----------------
// A (Wt) split hi/lo (x2 passes), B bf16-hi. All tiles staged via glds16 (pre-swizzled source).
// Output: bf16-hi, transposed layout [256][32768].
__global__ __launch_bounds__(256, 2) void gemm_small_k(
    const u16* __restrict__ Ah, const u16* __restrict__ Al,
    const u16* __restrict__ Bh,
    const float* __restrict__ bias, u16* __restrict__ Oh)
{
    __shared__ u16 sAh[4096], sAl[4096], sBh[4096];  // 128x32 each
    const int tid = threadIdx.x;
    const int w = tid >> 6, lane = tid & 63;
    const int i0 = blockIdx.x * 128;   // output row tile (hid')
    const int r0 = blockIdx.y * 128;   // output col tile (r)
    const int lr = lane & 15, lk = lane >> 4;
    const int wr = (w >> 1) * 64, wc = (w & 1) * 64;
    const int kslot = (lk ^ ((lr >> 1) & 3)) * 8;   // swizzled read slot (u16 units)
    const int cb = ((lane & 3) ^ ((lane >> 3) & 3)) * 8;  // pre-swizzled source slot

    const u16 *pAh[2], *pAl[2], *pBh[2];
#pragma unroll
    for (int j = 0; j < 2; ++j) {
        const int ra = i0 + (w * 2 + j) * 16 + (lane >> 2);
        pAh[j] = Ah + (size_t)ra * 256 + cb;
        pAl[j] = Al + (size_t)ra * 256 + cb;
        const int rb = r0 + (w * 2 + j) * 16 + (lane >> 2);
        pBh[j] = Bh + (size_t)rb * 256 + cb;
    }

    f4v acc[4][4] = {};

    for (int kt = 0; kt < 8; ++kt) {
#pragma unroll
        for (int j = 0; j < 2; ++j) {
            glds16(pAh[j] + kt * 32, sAh + (w * 2 + j) * 512);
            glds16(pAl[j] + kt * 32, sAl + (w * 2 + j) * 512);
            glds16(pBh[j] + kt * 32, sBh + (w * 2 + j) * 512);
        }
        __syncthreads();

        s8v fah[4], fal[4], fbh[4];
#pragma unroll
        for (int m = 0; m < 4; ++m) {
            fah[m] = *(const s8v*)(sAh + (wr + m * 16 + lr) * 32 + kslot);
            fal[m] = *(const s8v*)(sAl + (wr + m * 16 + lr) * 32 + kslot);
            fbh[m] = *(const s8v*)(sBh + (wc + m * 16 + lr) * 32 + kslot);
        }
#pragma unroll
        for (int m = 0; m < 4; ++m)
#pragma unroll
            for (int n = 0; n < 4; ++n)
                acc[m][n] = MFMA(fah[m], fbh[n], acc[m][n]);
#pragma unroll
        for (int m = 0; m < 4; ++m)
#pragma unroll
            for (int n = 0; n < 4; ++n)
                acc[m][n] = MFMA(fal[m], fbh[n], acc[m][n]);
        __syncthreads();
    }

    // epilogue: +bias, round to bf16-hi, store transposed output [hid'][32768]
#pragma unroll
    for (int m = 0; m < 4; ++m) {
#pragma unroll
        for (int q = 0; q < 4; ++q) {
            const int rowg = i0 + wr + m * 16 + lk * 4 + q;
            const float bv = bias[rowg];
#pragma unroll
            for (int n = 0; n < 4; ++n) {
                const int colg = r0 + wc + n * 16 + lr;
                float v = acc[m][n][q] + bv;
                Oh[(size_t)rowg * R_TOT + colg] = bf_rne(v);
            }
        }
    }
}

// ---------------- big GEMM: H[b][i=n][j=h] = relu( sum_m Ghi[i][m] * Thi[j][b*4096+m] ) ----------------
// Pure bf16 (x1). BM=256 BN=128 BK=64, 8 waves (4Mx2N, per-wave 64x64), triple-buffered
// LDS (3 x 48KB), 2 phases/K-tile (ks0 | ks1), counted vmcnt(6), setprio around MFMA.
// Row = 64 u16 = 128B; swizzle: slot s' = (ks*4+lk) ^ (row&7)  (8 slots x 16B, uniform banks).
// Staging: per-wave 1KB chunks (8 rows x 64 u16), source pre-swizzled by (l&7)^(l>>3).
// Buffer layout (u16): [A 256x64 | B 128x64] = 24576 u16 = 48KB. Output: bf16-hi only.
__global__ __launch_bounds__(512, 2) void gemm_big_k(
    const u16* __restrict__ Gh, const u16* __restrict__ Th,
    u16* __restrict__ Hh)
{
    extern __shared__ u16 lds[];   // 3 * 24576 u16 = 147456 B
    const int tid = threadIdx.x;
    const int w = tid >> 6, l = tid & 63;
    const int n0 = blockIdx.x * 256;
    const int h0 = blockIdx.y * 128;
    const int b  = blockIdx.z;
    const int lr = l & 15, lk = l >> 4;
    const int wm = w >> 1, wn = w & 1;
    // fragment read slots (u16 units): s' = (ks*4+lk) ^ (lr&7)
    const int sl0 = ((lk)     ^ (lr & 7)) * 8;
    const int sl1 = ((4 + lk) ^ (lr & 7)) * 8;

    // staging: per-lane source swizzle (chunk = 8 rows x 64 u16)
    const int srow  = l >> 3;                   // row within chunk
    const int sslot = ((l & 7) ^ srow) * 8;     // source col slot (u16)

    // A chunks c = w, w+8, w+16, w+24 (rows 8c..8c+7); B chunks c = w, w+8
    const u16* pA0 = Gh + (size_t)(n0 + 8 * w        + srow) * 4096 + sslot;
    const u16* pA1 = Gh + (size_t)(n0 + 8 * (w + 8)  + srow) * 4096 + sslot;
    const u16* pA2 = Gh + (size_t)(n0 + 8 * (w + 16) + srow) * 4096 + sslot;
    const u16* pA3 = Gh + (size_t)(n0 + 8 * (w + 24) + srow) * 4096 + sslot;
    const u16* pB0 = Th + (size_t)(h0 + 8 * w       + srow) * R_TOT + (size_t)b * 4096 + sslot;
    const u16* pB1 = Th + (size_t)(h0 + 8 * (w + 8) + srow) * R_TOT + (size_t)b * 4096 + sslot;

    // wave-uniform LDS chunk bases (u16)
    const int dA0 = w * 512, dA1 = (w + 8) * 512, dA2 = (w + 16) * 512, dA3 = (w + 24) * 512;
    const int dB0 = 16384 + w * 512, dB1 = 16384 + (w + 8) * 512;

    f4v acc[4][4] = {};

#define STAGE6(STG) do {                                                       \
    u16* Ls = lds + (STG) * 24576;                                             \
    glds16(pA0, Ls + dA0); glds16(pA1, Ls + dA1);                              \
    glds16(pA2, Ls + dA2); glds16(pA3, Ls + dA3);                              \
    glds16(pB0, Ls + dB0); glds16(pB1, Ls + dB1);                              \
    pA0 += 64; pA1 += 64; pA2 += 64; pA3 += 64; pB0 += 64; pB1 += 64;          \
} while (0)

// One K-tile: 2 phases. VMODE: 0 = vmcnt(6) (steady), 1 = vmcnt(0) (drain), 2 = skip.
#define KTILE(CUR, STG, DO_STAGE, VMODE) do {                                  \
    const u16* Lc = lds + (CUR) * 24576;                                       \
    u16* Ls = lds + (STG) * 24576;                                             \
    /* P0: ks0 fragments; stage first 3 chunks */                              \
    { s8v fa[4], fb[4];                                                        \
      _Pragma("unroll") for (int m = 0; m < 4; ++m)                            \
          fa[m] = *(const s8v*)(Lc + (wm * 64 + m * 16 + lr) * 64 + sl0);      \
      _Pragma("unroll") for (int n = 0; n < 4; ++n)                            \
          fb[n] = *(const s8v*)(Lc + 16384 + (wn * 64 + n * 16 + lr) * 64 + sl0); \
      if (DO_STAGE) { glds16(pA0, Ls + dA0); glds16(pA1, Ls + dA1);            \
                      glds16(pB0, Ls + dB0); }                                 \
      __builtin_amdgcn_s_barrier();                                            \
      __builtin_amdgcn_s_setprio(1);                                           \
      _Pragma("unroll") for (int m = 0; m < 4; ++m)                            \
          _Pragma("unroll") for (int n = 0; n < 4; ++n)                        \
              acc[m][n] = MFMA(fa[m], fb[n], acc[m][n]);                       \
      __builtin_amdgcn_s_setprio(0);                                           \
      __builtin_amdgcn_s_barrier(); }                                          \
    /* P1: ks1 fragments; stage last 3 chunks, advance ptrs */                 \
    { s8v fa[4], fb[4];                                                        \
      _Pragma("unroll") for (int m = 0; m < 4; ++m)                            \
          fa[m] = *(const s8v*)(Lc + (wm * 64 + m * 16 + lr) * 64 + sl1);      \
      _Pragma("unroll") for (int n = 0; n < 4; ++n)                            \
          fb[n] = *(const s8v*)(Lc + 16384 + (wn * 64 + n * 16 + lr) * 64 + sl1); \
      if (DO_STAGE) { glds16(pA2, Ls + dA2); glds16(pA3, Ls + dA3);            \
                      glds16(pB1, Ls + dB1);                                   \
                      pA0 += 64; pA1 += 64; pA2 += 64; pA3 += 64;              \
                      pB0 += 64; pB1 += 64; }                                  \
      __builtin_amdgcn_s_barrier();                                            \
      __builtin_amdgcn_s_setprio(1);                                           \
      _Pragma("unroll") for (int m = 0; m < 4; ++m)                            \
          _Pragma("unroll") for (int n = 0; n < 4; ++n)                        \
              acc[m][n] = MFMA(fa[m], fb[n], acc[m][n]);                       \
      __builtin_amdgcn_s_setprio(0); }                                         \
    if (VMODE == 0)      asm volatile("s_waitcnt vmcnt(6)" ::: "memory");      \
    else if (VMODE == 1) asm volatile("s_waitcnt vmcnt(0)" ::: "memory");      \
    if (VMODE != 2) __builtin_amdgcn_s_barrier();                              \
    __builtin_amdgcn_sched_barrier(0);                                         \
} while (0)

    // prologue: stage tiles 0 (buf0) and 1 (buf1); 12 loads in flight per wave
    STAGE6(0);
    STAGE6(1);
    asm volatile("s_waitcnt vmcnt(6)" ::: "memory");   // tile-0 loads landed
    __builtin_amdgcn_s_barrier();
    __builtin_amdgcn_sched_barrier(0);

    // 64 K-tiles: t in buf t%3, staging t+2 while computing t (t <= 61)
    for (int it = 0; it < 20; ++it) {
        KTILE(0, 2, 1, 0);
        KTILE(1, 0, 1, 0);
        KTILE(2, 1, 1, 0);
    }
    KTILE(0, 2, 1, 0);   // t=60, stages 62
    KTILE(1, 0, 1, 0);   // t=61, stages 63
    KTILE(2, 1, 0, 1);   // t=62, drain tile-63 loads
    KTILE(0, 2, 0, 2);   // t=63

#undef STAGE6
#undef KTILE

    // epilogue: relu, round, store H as bf16-hi [b*4096+row][col]
    const size_t obase = ((size_t)b * 4096 + n0 + wm * 64 + lk * 4) * 256
                       + h0 + wn * 64 + lr;
#pragma unroll
    for (int m = 0; m < 4; ++m)
#pragma unroll
        for (int n = 0; n < 4; ++n)
#pragma unroll
            for (int q = 0; q < 4; ++q) {
                float v = acc[m][n][q];
                v = v > 0.f ? v : 0.f;
                Hh[obase + (size_t)(m * 16 + q) * 256 + n * 16] = bf_rne(v);
            }
}

// ---------------- final MLP (MFMA): out[r] = relu(H[r,:] @ Wm1 + bm1) @ Wm2 + bm2 ----------------
// Per block (256 thr): stage Wm1^T bf16 into 32KB LDS (XOR-swizzled), 4 waves x 32 rows,
// K=256 via 8 x (2x4 MFMA) with A-frags loaded straight from global H-hi.
__global__ __launch_bounds__(256) void mlp_k(
    const u16* __restrict__ Hh, const float* __restrict__ Wm1,
    const float* __restrict__ bm1, const float* __restrict__ Wm2,
    const float* __restrict__ bm2, float* __restrict__ out)
{
    __shared__ u16 sB[16384];   // Wm1t bf16, swizzled: [col 64][k 256]
    const int tid = threadIdx.x;
    const int w = tid >> 6, l = tid & 63;
    const int lr = l & 15, lk = l >> 4;

    // stage Wm1^T: coalesced read Wm1[k][col], bf16 round, XOR-swizzled ds_write
    for (int idx = tid; idx < 16384; idx += 256) {
        const int col = idx & 63, k = idx >> 6;
        const int slot = (k >> 3) ^ (col & 7);
        sB[col * 256 + slot * 8 + (k & 7)] = bf_rne(Wm1[k * 64 + col]);
    }
    __syncthreads();

    // per-lane epilogue constants
    float bm1v[4], w2v[4];
#pragma unroll
    for (int n = 0; n < 4; ++n) {
        bm1v[n] = bm1[n * 16 + lr];
        w2v[n]  = Wm2[n * 16 + lr];
    }
    const float b2v = bm2[0];

    const int rowbase = blockIdx.x * 128 + w * 32;
    f4v acc[2][4] = {};
#pragma unroll
    for (int ks = 0; ks < 8; ++ks) {
        s8v fa[2], fb[4];
#pragma unroll
        for (int m = 0; m < 2; ++m)
            fa[m] = *(const s8v*)(Hh + (size_t)(rowbase + m * 16 + lr) * 256 + ks * 32 + lk * 8);
        const int slot = ((ks * 4 + lk) ^ (lr & 7)) * 8;
#pragma unroll
        for (int n = 0; n < 4; ++n)
            fb[n] = *(const s8v*)(sB + (n * 16 + lr) * 256 + slot);
#pragma unroll
        for (int m = 0; m < 2; ++m)
#pragma unroll
            for (int n = 0; n < 4; ++n)
                acc[m][n] = MFMA(fa[m], fb[n], acc[m][n]);
    }

    // epilogue: +bm1, relu, xWm2, reduce over 64 cols (16-lane butterfly), +bm2
#pragma unroll
    for (int m = 0; m < 2; ++m)
#pragma unroll
        for (int q = 0; q < 4; ++q) {
            float p = 0.f;
#pragma unroll
            for (int n = 0; n < 4; ++n) {
                float v = acc[m][n][q] + bm1v[n];
                v = v > 0.f ? v : 0.f;
                p += v * w2v[n];
            }
#pragma unroll
            for (int mask = 1; mask < 16; mask <<= 1)
                p += __shfl_xor(p, mask);
            if (lr == 0)
                out[rowbase + m * 16 + lk * 4 + q] = p + b2v;
        }
}

// ---------------- launch ----------------
extern "C" void kernel_launch(void* const* d_in, const int* in_sizes, int n_in,
                              void* d_out, int out_size, void* d_ws, size_t ws_size,
                              hipStream_t stream) {
    (void)in_sizes; (void)n_in; (void)out_size; (void)ws_size;
    const float* X   = (const float*)d_in[0];
    const float* G   = (const float*)d_in[1];
    const float* W1  = (const float*)d_in[2];
    const float* b1  = (const float*)d_in[3];
    const float* W2  = (const float*)d_in[4];
    const float* b2  = (const float*)d_in[5];
    const float* Wm1 = (const float*)d_in[6];
    const float* bm1 = (const float*)d_in[7];
    const float* Wm2 = (const float*)d_in[8];
    const float* bm2 = (const float*)d_in[9];
    float* out = (float*)d_out;

    char* ws = (char*)d_ws;
    u16* Gh   = (u16*)(ws);                     // 33554432 B (bf16 hi)
    u16* W1th = (u16*)(ws + 67108864u);         // 131072 B
    u16* W1tl = (u16*)(ws + 67239936u);
    u16* W2th = (u16*)(ws + 67371008u);
    u16* W2tl = (u16*)(ws + 67502080u);
    u16* Tth  = (u16*)(ws + 67633152u);         // 16777216 B (bf16 hi)
    u16* XHh  = (u16*)(ws + 101187584u);        // 16777216 B (X-hi, then H1-hi, then H2-hi)

    // split G and X to bf16-hi (fused); split+transpose W1/W2 (fused)
    splitGX_k<<<3072, 256, 0, stream>>>(G, Gh, X, XHh);
    splitT2_k<<<dim3(256, 2), 256, 0, stream>>>(W1, W1th, W1tl, W2, W2th, W2tl);

    // conv1 pre-prop: T1t = bf16((X @ W1 + b1)^T)
    gemm_small_k<<<dim3(2, 256), 256, 0, stream>>>(W1th, W1tl, XHh, b1, Tth);
    // conv1 prop: H1 = bf16(relu(G @ T1)) (overwrites X buffer)
    gemm_big_k<<<dim3(16, 2, 8), 512, 147456, stream>>>(Gh, Tth, XHh);
    // conv2 pre-prop: T2t = bf16((H1 @ W2 + b2)^T)
    gemm_small_k<<<dim3(2, 256), 256, 0, stream>>>(W2th, W2tl, XHh, b2, Tth);
    // conv2 prop: H2 = bf16(relu(G @ T2))
    gemm_big_k<<<dim3(16, 2, 8), 512, 147456, stream>>>(Gh, Tth, XHh);
    // final MLP (MFMA)
    mlp_k<<<256, 256, 0, stream>>>(XHh, Wm1, bm1, Wm2, bm2, out);
}